// Round 2
// baseline (24092.105 us; speedup 1.0000x reference)
//
#include <hip/hip_runtime.h>

typedef unsigned short u16;
typedef unsigned int u32;
typedef unsigned long long u64;
typedef __attribute__((ext_vector_type(8))) short bf16x8;
typedef __attribute__((ext_vector_type(4))) float f32x4;

#define SW(r) (((r) & 7) << 4)

__device__ __forceinline__ u16 f2bf(float f) {
  u32 x = __float_as_uint(f);
  x += 0x7fffu + ((x >> 16) & 1u);
  return (u16)(x >> 16);
}

union BF8 { bf16x8 v; u16 u[8]; u64 q[2]; };

__device__ __forceinline__ void gload_lds16(const void* g, void* l) {
  __builtin_amdgcn_global_load_lds(
      (const __attribute__((address_space(1))) u32*)g,
      (__attribute__((address_space(3))) u32*)l, 16, 0, 0);
}

// coherent 16B load: two relaxed agent-scope atomic u64 loads (emit sc1 -> L2 bypass,
// reads the cross-XCD coherence point without invalidating this XCD's L2)
__device__ __forceinline__ bf16x8 coh_load16(const u16* p) {
  BF8 r;
  r.q[0] = __hip_atomic_load((const u64*)p, __ATOMIC_RELAXED, __HIP_MEMORY_SCOPE_AGENT);
  r.q[1] = __hip_atomic_load((const u64*)(p + 4), __ATOMIC_RELAXED, __HIP_MEMORY_SCOPE_AGENT);
  return r.v;
}

__device__ __forceinline__ float fsigmoid(float x) { return 1.0f / (1.0f + __expf(-x)); }
__device__ __forceinline__ float ftanh(float x) {
  float a = fabsf(x);
  float t = __expf(-2.0f * a);
  float r = (1.0f - t) / (1.0f + t);
  return x < 0.0f ? -r : r;
}

// ---------------- prep: bf16 weight packs + padded concat input ----------------
__global__ void seqenc_prep(
    const float* __restrict__ state, const float* __restrict__ actions,
    const float* __restrict__ w0, const float* __restrict__ w1,
    const float* __restrict__ w2, const float* __restrict__ w3,
    const float* __restrict__ wih, const float* __restrict__ whh,
    const float* __restrict__ bih, const float* __restrict__ bhh,
    const float* __restrict__ wq, const float* __restrict__ wk, const float* __restrict__ wv,
    const float* __restrict__ bq, const float* __restrict__ bk, const float* __restrict__ bv,
    const float* __restrict__ wout,
    u16* __restrict__ Xpad, u16* __restrict__ Wcat, u16* __restrict__ Wqkv,
    u16* __restrict__ W0p, u16* __restrict__ W1b, u16* __restrict__ W2b,
    u16* __restrict__ W3b, u16* __restrict__ WoutB,
    float* __restrict__ bg, float* __restrict__ bqkv)
{
  const long NX = 25165824L, NC = 524288L, NQ = 196608L, N0P = 98304L;
  const long N1 = 262144L, N2 = 262144L, N3 = 131072L, NO = 65536L;
  const long NBG = 1024L, NBQ = 768L;
  const long TOT = NX + NC + NQ + N0P + N1 + N2 + N3 + NO + NBG + NBQ;
  for (long i = (long)blockIdx.x * blockDim.x + threadIdx.x; i < TOT;
       i += (long)gridDim.x * blockDim.x) {
    long j = i;
    if (j < NX) {  // Xpad[t*512 + b*8 + a][192] : [state(128) | actions(32) | 0(32)]
      long row = j / 192, col = j - row * 192;
      int t = (int)(row >> 9), r = (int)(row & 511);
      int b = r >> 3, a = r & 7;
      float v = 0.0f;
      if (col < 128) v = state[((long)(b * 256 + t)) * 128 + col];
      else if (col < 160) v = actions[(((long)(b * 256 + t)) * 8 + a) * 32 + (col - 128)];
      Xpad[j] = f2bf(v);
      continue;
    }
    j -= NX;
    if (j < NC) {  // Wcat[1024][512] = [w_ih | w_hh]
      long n = j >> 9, k = j & 511;
      float v = (k < 256) ? wih[n * 256 + k] : whh[n * 256 + (k - 256)];
      Wcat[j] = f2bf(v); continue;
    }
    j -= NC;
    if (j < NQ) {  // Wqkv[768][256]
      long n = j >> 8, k = j & 255;
      float v = (n < 256) ? wq[n * 256 + k] : (n < 512) ? wk[(n - 256) * 256 + k]
                                                        : wv[(n - 512) * 256 + k];
      Wqkv[j] = f2bf(v); continue;
    }
    j -= NQ;
    if (j < N0P) {  // W0p[512][192] zero-padded
      long n = j / 192, k = j - n * 192;
      W0p[j] = f2bf(k < 160 ? w0[n * 160 + k] : 0.0f); continue;
    }
    j -= N0P;
    if (j < N1) { W1b[j] = f2bf(w1[j]); continue; }
    j -= N1;
    if (j < N2) { W2b[j] = f2bf(w2[j]); continue; }
    j -= N2;
    if (j < N3) { W3b[j] = f2bf(w3[j]); continue; }
    j -= N3;
    if (j < NO) { WoutB[j] = f2bf(wout[j]); continue; }
    j -= NO;
    if (j < NBG) { bg[j] = bih[j] + bhh[j]; continue; }
    j -= NBG;
    bqkv[j] = (j < 256) ? bq[j] : (j < 512) ? bk[j - 256] : bv[j - 512];
  }
}

// ---------------- MLP GEMM: C[M][N] = act(A[M][K] @ B[N][K]^T + bias) ----------------
__global__ __launch_bounds__(256) void seqenc_gemm(
    const u16* __restrict__ A, const u16* __restrict__ B,
    const float* __restrict__ bias, u16* __restrict__ C,
    int K, int N, int relu)
{
  __shared__ char As[16384];
  __shared__ char Bs[16384];
  const int tid = threadIdx.x;
  const int m0 = blockIdx.x * 128, n0 = blockIdx.y * 128;
  const int wid = tid >> 6, lane = tid & 63;
  const int wm = (wid >> 1) * 64, wn = (wid & 1) * 64;
  const int lr = lane & 15, kq = lane >> 4;
  f32x4 acc[4][4] = {};
  for (int kt = 0; kt < K; kt += 64) {
#pragma unroll
    for (int i2 = 0; i2 < 4; ++i2) {
      int q = i2 * 256 + tid;
      int r = q >> 3, cb = (q & 7) << 4;
      int scb = cb ^ SW(r);
      gload_lds16(A + (size_t)(m0 + r) * K + kt + (scb >> 1), As + q * 16);
      gload_lds16(B + (size_t)(n0 + r) * K + kt + (scb >> 1), Bs + q * 16);
    }
    __syncthreads();
#pragma unroll
    for (int ks = 0; ks < 2; ++ks) {
      bf16x8 af[4], bfr[4];
      int kb = ks * 64 + (kq << 4);
#pragma unroll
      for (int tt = 0; tt < 4; ++tt) {
        int ra = wm + tt * 16 + lr;
        af[tt] = *(const bf16x8*)(As + ra * 128 + (kb ^ SW(ra)));
        int rb = wn + tt * 16 + lr;
        bfr[tt] = *(const bf16x8*)(Bs + rb * 128 + (kb ^ SW(rb)));
      }
#pragma unroll
      for (int mt = 0; mt < 4; ++mt)
#pragma unroll
        for (int nt = 0; nt < 4; ++nt)
          acc[mt][nt] = __builtin_amdgcn_mfma_f32_16x16x32_bf16(af[mt], bfr[nt], acc[mt][nt], 0, 0, 0);
    }
    __syncthreads();
  }
#pragma unroll
  for (int mt = 0; mt < 4; ++mt) {
#pragma unroll
    for (int nt = 0; nt < 4; ++nt) {
      int gn = n0 + wn + nt * 16 + lr;
      float bv = bias[gn];
#pragma unroll
      for (int rr = 0; rr < 4; ++rr) {
        int gm = m0 + wm + mt * 16 + (kq << 2) + rr;
        float v = acc[mt][nt][rr] + bv;
        if (relu) v = fmaxf(v, 0.0f);
        C[(size_t)gm * N + gn] = f2bf(v);
      }
    }
  }
}

// ---------------- persistent recurrent kernel: 32 WGs x 512 thr, 16 rows each ----------------
__global__ __launch_bounds__(512) void seqenc_recurrent(
    const u16* __restrict__ X4, const u16* __restrict__ Wcat, const float* __restrict__ bg,
    const u16* __restrict__ Wqkv, const float* __restrict__ bqkv,
    u16* kbuf, u16* vt,
    const u16* __restrict__ WoutB, const float* __restrict__ bout,
    const float* __restrict__ h0g, const float* __restrict__ c0g,
    float* __restrict__ dout, unsigned* ctr)
{
  __shared__ float sc[16 * 256];       // c state (f32)
  __shared__ float sh[16 * 256];       // h state (f32)
  __shared__ float sosum[16 * 256];    // sum over t of h_post
  __shared__ char shb[16 * 512];       // h bf16, XOR-swizzled
  __shared__ char sqb[16 * 512];       // q bf16, XOR-swizzled
  __shared__ char spb[16 * 1024];      // P bf16, XOR-swizzled
  __shared__ float scratch[16 * 1028]; // gates / qkv / S staging

  const int tid = threadIdx.x;
  const int lane = tid & 63, wid = tid >> 6;
  const int lr = lane & 15, kq = lane >> 4;
  const int r0 = blockIdx.x * 16;

  {
    int r = tid >> 5, c8 = (tid & 31) * 8;
    BF8 hv;
#pragma unroll
    for (int j2 = 0; j2 < 8; ++j2) {
      float h = h0g[(size_t)(r0 + r) * 256 + c8 + j2];
      float c = c0g[(size_t)(r0 + r) * 256 + c8 + j2];
      sh[r * 256 + c8 + j2] = h;
      sc[r * 256 + c8 + j2] = c;
      sosum[r * 256 + c8 + j2] = 0.0f;
      hv.u[j2] = f2bf(h);
    }
    *(bf16x8*)(shb + r * 512 + ((c8 * 2) ^ SW(r))) = hv.v;
  }
  __syncthreads();

  for (int t = 0; t < 256; ++t) {
    // ---- Phase A: gates = [x_t | h] @ Wcat^T + bg  (K=512, N=1024) ----
    bf16x8 xf[8], hf[8];
#pragma unroll
    for (int ks = 0; ks < 8; ++ks) {
      xf[ks] = *(const bf16x8*)(X4 + (size_t)((t << 9) + r0 + lr) * 256 + ks * 32 + (kq << 3));
      hf[ks] = *(const bf16x8*)(shb + lr * 512 + ((ks * 64 + (kq << 4)) ^ SW(lr)));
    }
#pragma unroll
    for (int nt = 0; nt < 8; ++nt) {
      const int gn0 = wid * 128 + nt * 16;
      const u16* bp = Wcat + (size_t)(gn0 + lr) * 512 + (kq << 3);
      f32x4 a4 = {0.0f, 0.0f, 0.0f, 0.0f};
#pragma unroll
      for (int ks = 0; ks < 16; ++ks) {
        bf16x8 bw = *(const bf16x8*)(bp + ks * 32);
        a4 = __builtin_amdgcn_mfma_f32_16x16x32_bf16(ks < 8 ? xf[ks] : hf[ks - 8], bw, a4, 0, 0, 0);
      }
      float bb = bg[gn0 + lr];
#pragma unroll
      for (int rr = 0; rr < 4; ++rr)
        scratch[(kq * 4 + rr) * 1028 + gn0 + lr] = a4[rr] + bb;
    }
    __syncthreads();

    // ---- Phase B: LSTM pointwise update ----
    {
      int r = tid >> 5, c8 = (tid & 31) * 8;
      BF8 hv;
#pragma unroll
      for (int j2 = 0; j2 < 8; ++j2) {
        int c = c8 + j2;
        float iv = fsigmoid(scratch[r * 1028 + c]);
        float fv = fsigmoid(scratch[r * 1028 + 256 + c]);
        float gv = ftanh(scratch[r * 1028 + 512 + c]);
        float ov = fsigmoid(scratch[r * 1028 + 768 + c]);
        float cn = fv * sc[r * 256 + c] + iv * gv;
        float hn = ov * ftanh(cn);
        sc[r * 256 + c] = cn;
        sh[r * 256 + c] = hn;
        hv.u[j2] = f2bf(hn);
      }
      *(bf16x8*)(shb + r * 512 + ((c8 * 2) ^ SW(r))) = hv.v;
    }
    __syncthreads();

    // ---- Phase C: qkv = h_pre @ Wqkv^T + bqkv  (K=256, N=768) ----
    {
      bf16x8 hp[8];
#pragma unroll
      for (int ks = 0; ks < 8; ++ks)
        hp[ks] = *(const bf16x8*)(shb + lr * 512 + ((ks * 64 + (kq << 4)) ^ SW(lr)));
#pragma unroll
      for (int nt = 0; nt < 6; ++nt) {
        const int gn0 = wid * 96 + nt * 16;
        const u16* bp = Wqkv + (size_t)(gn0 + lr) * 256 + (kq << 3);
        f32x4 a4 = {0.0f, 0.0f, 0.0f, 0.0f};
#pragma unroll
        for (int ks = 0; ks < 8; ++ks)
          a4 = __builtin_amdgcn_mfma_f32_16x16x32_bf16(hp[ks], *(const bf16x8*)(bp + ks * 32), a4, 0, 0, 0);
        float bb = bqkv[gn0 + lr];
#pragma unroll
        for (int rr = 0; rr < 4; ++rr)
          scratch[(kq * 4 + rr) * 772 + gn0 + lr] = a4[rr] + bb;
      }
    }
    __syncthreads();

    // ---- Phase D: publish k (row-major) and v^T; q -> LDS ----
    {
      u16* kb = kbuf + (size_t)(t & 1) * 131072;
      u16* vb = vt + (size_t)(t & 1) * 131072;
      int r = tid >> 5, c8 = (tid & 31) * 8;
      BF8 qv, kv;
#pragma unroll
      for (int j2 = 0; j2 < 8; ++j2) {
        qv.u[j2] = f2bf(scratch[r * 772 + c8 + j2]);
        kv.u[j2] = f2bf(scratch[r * 772 + 256 + c8 + j2]);
      }
      *(bf16x8*)(sqb + r * 512 + ((c8 * 2) ^ SW(r))) = qv.v;
      *(bf16x8*)(kb + (size_t)(r0 + r) * 256 + c8) = kv.v;
      int d = tid >> 1, h8 = (tid & 1) * 8;
      BF8 vv;
#pragma unroll
      for (int j2 = 0; j2 < 8; ++j2)
        vv.u[j2] = f2bf(scratch[(h8 + j2) * 772 + 512 + d]);
      *(bf16x8*)(vb + (size_t)d * 512 + r0 + h8) = vv.v;
    }

    // ---- grid barrier (one per step): RELEASE add (wbl2, no invalidate), RELAXED spin ----
    __syncthreads();
    if (tid == 0) {
      __hip_atomic_fetch_add(ctr, 1u, __ATOMIC_RELEASE, __HIP_MEMORY_SCOPE_AGENT);
      unsigned target = 32u * (unsigned)(t + 1);
      unsigned v = 0, sp = 0;
      do {
        v = __hip_atomic_load(ctr, __ATOMIC_RELAXED, __HIP_MEMORY_SCOPE_AGENT);
      } while (v < target && ++sp < 100000000u);
    }
    __syncthreads();

    // ---- Phase E: S = q @ k^T over all 512 keys, softmax ----
    {
      const u16* kb = kbuf + (size_t)(t & 1) * 131072;
      bf16x8 qf[8];
#pragma unroll
      for (int ks = 0; ks < 8; ++ks)
        qf[ks] = *(const bf16x8*)(sqb + lr * 512 + ((ks * 64 + (kq << 4)) ^ SW(lr)));
#pragma unroll
      for (int nt = 0; nt < 4; ++nt) {
        const int key0 = wid * 64 + nt * 16;
        const u16* bp = kb + (size_t)(key0 + lr) * 256 + (kq << 3);
        bf16x8 kf[8];
#pragma unroll
        for (int ks = 0; ks < 8; ++ks)
          kf[ks] = coh_load16(bp + ks * 32);
        f32x4 a4 = {0.0f, 0.0f, 0.0f, 0.0f};
#pragma unroll
        for (int ks = 0; ks < 8; ++ks)
          a4 = __builtin_amdgcn_mfma_f32_16x16x32_bf16(qf[ks], kf[ks], a4, 0, 0, 0);
#pragma unroll
        for (int rr = 0; rr < 4; ++rr)
          scratch[(kq * 4 + rr) * 516 + key0 + lr] = a4[rr];
      }
    }
    __syncthreads();
    {
      int r = tid >> 5, l32 = tid & 31;
      float vals[16];
      float m = -3.4e38f;
#pragma unroll
      for (int j2 = 0; j2 < 16; ++j2) {
        vals[j2] = scratch[r * 516 + l32 + j2 * 32];
        m = fmaxf(m, vals[j2]);
      }
#pragma unroll
      for (int s2 = 16; s2 > 0; s2 >>= 1) m = fmaxf(m, __shfl_xor(m, s2, 32));
      float sum = 0.0f;
#pragma unroll
      for (int j2 = 0; j2 < 16; ++j2) {
        vals[j2] = __expf((vals[j2] - m) * 0.0625f);
        sum += vals[j2];
      }
#pragma unroll
      for (int s2 = 16; s2 > 0; s2 >>= 1) sum += __shfl_xor(sum, s2, 32);
      float inv = 1.0f / sum;
#pragma unroll
      for (int j2 = 0; j2 < 16; ++j2) {
        int c = l32 + j2 * 32;
        *(u16*)(spb + r * 1024 + ((c * 2) ^ SW(r))) = f2bf(vals[j2] * inv);
      }
    }
    __syncthreads();

    // ---- Phase F: h += P @ V (via v^T), accumulate outs ----
    {
      const u16* vb = vt + (size_t)(t & 1) * 131072;
      bf16x8 pf[16];
#pragma unroll
      for (int ks = 0; ks < 16; ++ks)
        pf[ks] = *(const bf16x8*)(spb + lr * 1024 + ((ks * 64 + (kq << 4)) ^ SW(lr)));
#pragma unroll
      for (int nt = 0; nt < 2; ++nt) {
        const int d0 = wid * 32 + nt * 16;
        const u16* bp = vb + (size_t)(d0 + lr) * 512 + (kq << 3);
        bf16x8 vf[16];
#pragma unroll
        for (int ks = 0; ks < 16; ++ks)
          vf[ks] = coh_load16(bp + ks * 32);
        f32x4 a4 = {0.0f, 0.0f, 0.0f, 0.0f};
#pragma unroll
        for (int ks = 0; ks < 16; ++ks)
          a4 = __builtin_amdgcn_mfma_f32_16x16x32_bf16(pf[ks], vf[ks], a4, 0, 0, 0);
#pragma unroll
        for (int rr = 0; rr < 4; ++rr) {
          int row = kq * 4 + rr, col = d0 + lr;
          int idx = row * 256 + col;
          float hn = sh[idx] + a4[rr];
          sh[idx] = hn;
          sosum[idx] += hn;
          *(u16*)(shb + row * 512 + ((col * 2) ^ SW(row))) = f2bf(hn);
        }
      }
    }
    __syncthreads();
  }

  // ---- tail: out = (osum/256) @ Wout^T + bout ----
  {
    int r = tid >> 5, c8 = (tid & 31) * 8;
    BF8 ov;
#pragma unroll
    for (int j2 = 0; j2 < 8; ++j2)
      ov.u[j2] = f2bf(sosum[r * 256 + c8 + j2] * (1.0f / 256.0f));
    *(bf16x8*)(shb + r * 512 + ((c8 * 2) ^ SW(r))) = ov.v;
  }
  __syncthreads();
  {
    bf16x8 of[8];
#pragma unroll
    for (int ks = 0; ks < 8; ++ks)
      of[ks] = *(const bf16x8*)(shb + lr * 512 + ((ks * 64 + (kq << 4)) ^ SW(lr)));
#pragma unroll
    for (int nt = 0; nt < 2; ++nt) {
      const int gn = wid * 32 + nt * 16 + lr;
      const u16* bp = WoutB + (size_t)gn * 256 + (kq << 3);
      f32x4 a4 = {0.0f, 0.0f, 0.0f, 0.0f};
#pragma unroll
      for (int ks = 0; ks < 8; ++ks)
        a4 = __builtin_amdgcn_mfma_f32_16x16x32_bf16(of[ks], *(const bf16x8*)(bp + ks * 32), a4, 0, 0, 0);
      float bb = bout[gn];
#pragma unroll
      for (int rr = 0; rr < 4; ++rr)
        dout[(size_t)(r0 + kq * 4 + rr) * 256 + gn] = a4[rr] + bb;
    }
  }
}

extern "C" void kernel_launch(void* const* d_in, const int* in_sizes, int n_in,
                              void* d_out, int out_size, void* d_ws, size_t ws_size,
                              hipStream_t stream) {
  (void)in_sizes; (void)n_in; (void)out_size; (void)ws_size;
  const float* state = (const float*)d_in[0];
  const float* actions = (const float*)d_in[1];
  const float* h0 = (const float*)d_in[2];
  const float* c0 = (const float*)d_in[3];
  const float* w0 = (const float*)d_in[4];
  const float* b0 = (const float*)d_in[5];
  const float* w1 = (const float*)d_in[6];
  const float* b1 = (const float*)d_in[7];
  const float* w2 = (const float*)d_in[8];
  const float* b2 = (const float*)d_in[9];
  const float* w3 = (const float*)d_in[10];
  const float* b3 = (const float*)d_in[11];
  const float* wih = (const float*)d_in[12];
  const float* whh = (const float*)d_in[13];
  const float* bih = (const float*)d_in[14];
  const float* bhh = (const float*)d_in[15];
  const float* wq = (const float*)d_in[16];
  const float* bq = (const float*)d_in[17];
  const float* wk = (const float*)d_in[18];
  const float* bk = (const float*)d_in[19];
  const float* wv = (const float*)d_in[20];
  const float* bv = (const float*)d_in[21];
  const float* wout = (const float*)d_in[22];
  const float* bout = (const float*)d_in[23];

  char* ws = (char*)d_ws;
  size_t off = 0;
  auto take = [&](size_t bytes) {
    off = (off + 255) & ~(size_t)255;
    char* p = ws + off;
    off += bytes;
    return p;
  };
  u16* Xpad  = (u16*)take(131072UL * 192 * 2);
  u16* ping  = (u16*)take(32768UL * 512 * 2);
  u16* pong  = (u16*)take(32768UL * 512 * 2);
  u16* X4    = (u16*)take(131072UL * 256 * 2);
  u16* W0p   = (u16*)take(512UL * 192 * 2);
  u16* W1b   = (u16*)take(512UL * 512 * 2);
  u16* W2b   = (u16*)take(512UL * 512 * 2);
  u16* W3b   = (u16*)take(256UL * 512 * 2);
  u16* Wcat  = (u16*)take(1024UL * 512 * 2);
  u16* Wqkv  = (u16*)take(768UL * 256 * 2);
  u16* WoutB = (u16*)take(256UL * 256 * 2);
  float* bg   = (float*)take(1024UL * 4);
  float* bqkvp = (float*)take(768UL * 4);
  u16* kbuf  = (u16*)take(2UL * 512 * 256 * 2);
  u16* vtb   = (u16*)take(2UL * 256 * 512 * 2);
  unsigned* ctr = (unsigned*)take(256);

  hipMemsetAsync(ctr, 0, 256, stream);
  seqenc_prep<<<2048, 256, 0, stream>>>(state, actions, w0, w1, w2, w3, wih, whh, bih, bhh,
                                        wq, wk, wv, bq, bk, bv, wout,
                                        Xpad, Wcat, Wqkv, W0p, W1b, W2b, W3b, WoutB, bg, bqkvp);
  const int CM = 32768;
  for (int c = 0; c < 4; ++c) {
    const u16* a0 = Xpad + (size_t)c * CM * 192;
    u16* x4c = X4 + (size_t)c * CM * 256;
    seqenc_gemm<<<dim3(CM / 128, 4), 256, 0, stream>>>(a0, W0p, b0, ping, 192, 512, 1);
    seqenc_gemm<<<dim3(CM / 128, 4), 256, 0, stream>>>(ping, W1b, b1, pong, 512, 512, 1);
    seqenc_gemm<<<dim3(CM / 128, 4), 256, 0, stream>>>(pong, W2b, b2, ping, 512, 512, 1);
    seqenc_gemm<<<dim3(CM / 128, 2), 256, 0, stream>>>(ping, W3b, b3, x4c, 512, 256, 0);
  }
  seqenc_recurrent<<<32, 512, 0, stream>>>(X4, Wcat, bg, Wqkv, bqkvp, kbuf, vtb,
                                           WoutB, bout, h0, c0, (float*)d_out, ctr);
}

// Round 3
// 21051.962 us; speedup vs baseline: 1.1444x; 1.1444x over previous
//
#include <hip/hip_runtime.h>

typedef unsigned short u16;
typedef unsigned int u32;
typedef unsigned long long u64;
typedef __attribute__((ext_vector_type(8))) short bf16x8;
typedef __attribute__((ext_vector_type(4))) float f32x4;

#define SW(r) (((r) & 7) << 4)

__device__ __forceinline__ u16 f2bf(float f) {
  u32 x = __float_as_uint(f);
  x += 0x7fffu + ((x >> 16) & 1u);
  return (u16)(x >> 16);
}

union BF8 { bf16x8 v; u16 u[8]; };

__device__ __forceinline__ void gload_lds16(const void* g, void* l) {
  __builtin_amdgcn_global_load_lds(
      (const __attribute__((address_space(1))) u32*)g,
      (__attribute__((address_space(3))) u32*)l, 16, 0, 0);
}

// coherent 16B ops: plain pipelined VMEM with sc0 sc1 (bypass L1+L2, L3 is coherence point)
__device__ __forceinline__ bf16x8 cload16(const u16* p) {
  bf16x8 r;
  asm volatile("global_load_dwordx4 %0, %1, off sc0 sc1" : "=v"(r) : "v"(p));
  return r;
}
__device__ __forceinline__ void cstore16(u16* p, bf16x8 v) {
  asm volatile("global_store_dwordx4 %0, %1, off sc0 sc1" :: "v"(p), "v"(v) : "memory");
}

#define WAITV0 { asm volatile("s_waitcnt vmcnt(0)" ::: "memory"); __builtin_amdgcn_sched_barrier(0); }
#define WAITV8 { asm volatile("s_waitcnt vmcnt(8)" ::: "memory"); __builtin_amdgcn_sched_barrier(0); }

__device__ __forceinline__ float fsigmoid(float x) { return 1.0f / (1.0f + __expf(-x)); }
__device__ __forceinline__ float ftanh(float x) {
  float a = fabsf(x);
  float t = __expf(-2.0f * a);
  float r = (1.0f - t) / (1.0f + t);
  return x < 0.0f ? -r : r;
}

// ---------------- prep: bf16 weight packs + padded concat input ----------------
__global__ void seqenc_prep(
    const float* __restrict__ state, const float* __restrict__ actions,
    const float* __restrict__ w0, const float* __restrict__ w1,
    const float* __restrict__ w2, const float* __restrict__ w3,
    const float* __restrict__ wih, const float* __restrict__ whh,
    const float* __restrict__ bih, const float* __restrict__ bhh,
    const float* __restrict__ wq, const float* __restrict__ wk, const float* __restrict__ wv,
    const float* __restrict__ bq, const float* __restrict__ bk, const float* __restrict__ bv,
    const float* __restrict__ wout,
    u16* __restrict__ Xpad, u16* __restrict__ Wcat, u16* __restrict__ Wqkv,
    u16* __restrict__ W0p, u16* __restrict__ W1b, u16* __restrict__ W2b,
    u16* __restrict__ W3b, u16* __restrict__ WoutB,
    float* __restrict__ bg, float* __restrict__ bqkv)
{
  const long NX = 25165824L, NC = 524288L, NQ = 196608L, N0P = 98304L;
  const long N1 = 262144L, N2 = 262144L, N3 = 131072L, NO = 65536L;
  const long NBG = 1024L, NBQ = 768L;
  const long TOT = NX + NC + NQ + N0P + N1 + N2 + N3 + NO + NBG + NBQ;
  for (long i = (long)blockIdx.x * blockDim.x + threadIdx.x; i < TOT;
       i += (long)gridDim.x * blockDim.x) {
    long j = i;
    if (j < NX) {  // Xpad[t*512 + b*8 + a][192] : [state(128) | actions(32) | 0(32)]
      long row = j / 192, col = j - row * 192;
      int t = (int)(row >> 9), r = (int)(row & 511);
      int b = r >> 3, a = r & 7;
      float v = 0.0f;
      if (col < 128) v = state[((long)(b * 256 + t)) * 128 + col];
      else if (col < 160) v = actions[(((long)(b * 256 + t)) * 8 + a) * 32 + (col - 128)];
      Xpad[j] = f2bf(v);
      continue;
    }
    j -= NX;
    if (j < NC) {  // Wcat[1024][512] = [w_ih | w_hh]
      long n = j >> 9, k = j & 511;
      float v = (k < 256) ? wih[n * 256 + k] : whh[n * 256 + (k - 256)];
      Wcat[j] = f2bf(v); continue;
    }
    j -= NC;
    if (j < NQ) {  // Wqkv[768][256]
      long n = j >> 8, k = j & 255;
      float v = (n < 256) ? wq[n * 256 + k] : (n < 512) ? wk[(n - 256) * 256 + k]
                                                        : wv[(n - 512) * 256 + k];
      Wqkv[j] = f2bf(v); continue;
    }
    j -= NQ;
    if (j < N0P) {  // W0p[512][192] zero-padded
      long n = j / 192, k = j - n * 192;
      W0p[j] = f2bf(k < 160 ? w0[n * 160 + k] : 0.0f); continue;
    }
    j -= N0P;
    if (j < N1) { W1b[j] = f2bf(w1[j]); continue; }
    j -= N1;
    if (j < N2) { W2b[j] = f2bf(w2[j]); continue; }
    j -= N2;
    if (j < N3) { W3b[j] = f2bf(w3[j]); continue; }
    j -= N3;
    if (j < NO) { WoutB[j] = f2bf(wout[j]); continue; }
    j -= NO;
    if (j < NBG) { bg[j] = bih[j] + bhh[j]; continue; }
    j -= NBG;
    bqkv[j] = (j < 256) ? bq[j] : (j < 512) ? bk[j - 256] : bv[j - 512];
  }
}

// ---------------- MLP GEMM: C[M][N] = act(A[M][K] @ B[N][K]^T + bias) ----------------
__global__ __launch_bounds__(256) void seqenc_gemm(
    const u16* __restrict__ A, const u16* __restrict__ B,
    const float* __restrict__ bias, u16* __restrict__ C,
    int K, int N, int relu)
{
  __shared__ char As[16384];
  __shared__ char Bs[16384];
  const int tid = threadIdx.x;
  const int m0 = blockIdx.x * 128, n0 = blockIdx.y * 128;
  const int wid = tid >> 6, lane = tid & 63;
  const int wm = (wid >> 1) * 64, wn = (wid & 1) * 64;
  const int lr = lane & 15, kq = lane >> 4;
  f32x4 acc[4][4] = {};
  for (int kt = 0; kt < K; kt += 64) {
#pragma unroll
    for (int i2 = 0; i2 < 4; ++i2) {
      int q = i2 * 256 + tid;
      int r = q >> 3, cb = (q & 7) << 4;
      int scb = cb ^ SW(r);
      gload_lds16(A + (size_t)(m0 + r) * K + kt + (scb >> 1), As + q * 16);
      gload_lds16(B + (size_t)(n0 + r) * K + kt + (scb >> 1), Bs + q * 16);
    }
    __syncthreads();
#pragma unroll
    for (int ks = 0; ks < 2; ++ks) {
      bf16x8 af[4], bfr[4];
      int kb = ks * 64 + (kq << 4);
#pragma unroll
      for (int tt = 0; tt < 4; ++tt) {
        int ra = wm + tt * 16 + lr;
        af[tt] = *(const bf16x8*)(As + ra * 128 + (kb ^ SW(ra)));
        int rb = wn + tt * 16 + lr;
        bfr[tt] = *(const bf16x8*)(Bs + rb * 128 + (kb ^ SW(rb)));
      }
#pragma unroll
      for (int mt = 0; mt < 4; ++mt)
#pragma unroll
        for (int nt = 0; nt < 4; ++nt)
          acc[mt][nt] = __builtin_amdgcn_mfma_f32_16x16x32_bf16(af[mt], bfr[nt], acc[mt][nt], 0, 0, 0);
    }
    __syncthreads();
  }
#pragma unroll
  for (int mt = 0; mt < 4; ++mt) {
#pragma unroll
    for (int nt = 0; nt < 4; ++nt) {
      int gn = n0 + wn + nt * 16 + lr;
      float bv = bias[gn];
#pragma unroll
      for (int rr = 0; rr < 4; ++rr) {
        int gm = m0 + wm + mt * 16 + (kq << 2) + rr;
        float v = acc[mt][nt][rr] + bv;
        if (relu) v = fmaxf(v, 0.0f);
        C[(size_t)gm * N + gn] = f2bf(v);
      }
    }
  }
}

// ---------------- persistent recurrent kernel: 32 WGs x 512 thr, 16 rows each ----------------
__global__ __launch_bounds__(512) void seqenc_recurrent(
    const u16* __restrict__ X4, const u16* __restrict__ Wcat, const float* __restrict__ bg,
    const u16* __restrict__ Wqkv, const float* __restrict__ bqkv,
    u16* kbuf, u16* vt,
    const u16* __restrict__ WoutB, const float* __restrict__ bout,
    const float* __restrict__ h0g, const float* __restrict__ c0g,
    float* __restrict__ dout, unsigned* ctr)
{
  __shared__ float sc[16 * 256];       // c state (f32)
  __shared__ float sh[16 * 256];       // h state (f32)
  __shared__ float sosum[16 * 256];    // sum over t of h_post
  __shared__ char shb[16 * 512];       // h bf16, XOR-swizzled
  __shared__ char sqb[16 * 512];       // q bf16, XOR-swizzled
  __shared__ char spb[16 * 1024];      // P bf16, XOR-swizzled
  __shared__ float scratch[16 * 1028]; // gates / qkv / S staging

  const int tid = threadIdx.x;
  const int lane = tid & 63, wid = tid >> 6;
  const int lr = lane & 15, kq = lane >> 4;
  const int r0 = blockIdx.x * 16;

  {
    int r = tid >> 5, c8 = (tid & 31) * 8;
    BF8 hv;
#pragma unroll
    for (int j2 = 0; j2 < 8; ++j2) {
      float h = h0g[(size_t)(r0 + r) * 256 + c8 + j2];
      float c = c0g[(size_t)(r0 + r) * 256 + c8 + j2];
      sh[r * 256 + c8 + j2] = h;
      sc[r * 256 + c8 + j2] = c;
      sosum[r * 256 + c8 + j2] = 0.0f;
      hv.u[j2] = f2bf(h);
    }
    *(bf16x8*)(shb + r * 512 + ((c8 * 2) ^ SW(r))) = hv.v;
  }
  __syncthreads();

  for (int t = 0; t < 256; ++t) {
    bf16x8 kA[8], kB[8], vA[8], vB[8];
    // ---- Phase A: gates = [x_t | h] @ Wcat^T + bg  (K=512, N=1024) ----
    {
      bf16x8 xf[8], hf[8];
#pragma unroll
      for (int ks = 0; ks < 8; ++ks) {
        xf[ks] = *(const bf16x8*)(X4 + (size_t)((t << 9) + r0 + lr) * 256 + ks * 32 + (kq << 3));
        hf[ks] = *(const bf16x8*)(shb + lr * 512 + ((ks * 64 + (kq << 4)) ^ SW(lr)));
      }
#pragma unroll
      for (int nt = 0; nt < 8; ++nt) {
        const int gn0 = wid * 128 + nt * 16;
        const u16* bp = Wcat + (size_t)(gn0 + lr) * 512 + (kq << 3);
        f32x4 a4 = {0.0f, 0.0f, 0.0f, 0.0f};
#pragma unroll
        for (int ks = 0; ks < 16; ++ks) {
          bf16x8 bw = *(const bf16x8*)(bp + ks * 32);
          a4 = __builtin_amdgcn_mfma_f32_16x16x32_bf16(ks < 8 ? xf[ks] : hf[ks - 8], bw, a4, 0, 0, 0);
        }
        float bb = bg[gn0 + lr];
#pragma unroll
        for (int rr = 0; rr < 4; ++rr)
          scratch[(kq * 4 + rr) * 1028 + gn0 + lr] = a4[rr] + bb;
      }
    }
    __syncthreads();

    // ---- Phase B: LSTM pointwise update ----
    {
      int r = tid >> 5, c8 = (tid & 31) * 8;
      BF8 hv;
#pragma unroll
      for (int j2 = 0; j2 < 8; ++j2) {
        int c = c8 + j2;
        float iv = fsigmoid(scratch[r * 1028 + c]);
        float fv = fsigmoid(scratch[r * 1028 + 256 + c]);
        float gv = ftanh(scratch[r * 1028 + 512 + c]);
        float ov = fsigmoid(scratch[r * 1028 + 768 + c]);
        float cn = fv * sc[r * 256 + c] + iv * gv;
        float hn = ov * ftanh(cn);
        sc[r * 256 + c] = cn;
        sh[r * 256 + c] = hn;
        hv.u[j2] = f2bf(hn);
      }
      *(bf16x8*)(shb + r * 512 + ((c8 * 2) ^ SW(r))) = hv.v;
    }
    __syncthreads();

    // ---- Phase C: qkv = h_pre @ Wqkv^T + bqkv  (K=256, N=768) ----
    {
      bf16x8 hp[8];
#pragma unroll
      for (int ks = 0; ks < 8; ++ks)
        hp[ks] = *(const bf16x8*)(shb + lr * 512 + ((ks * 64 + (kq << 4)) ^ SW(lr)));
#pragma unroll
      for (int nt = 0; nt < 6; ++nt) {
        const int gn0 = wid * 96 + nt * 16;
        const u16* bp = Wqkv + (size_t)(gn0 + lr) * 256 + (kq << 3);
        f32x4 a4 = {0.0f, 0.0f, 0.0f, 0.0f};
#pragma unroll
        for (int ks = 0; ks < 8; ++ks)
          a4 = __builtin_amdgcn_mfma_f32_16x16x32_bf16(hp[ks], *(const bf16x8*)(bp + ks * 32), a4, 0, 0, 0);
        float bb = bqkv[gn0 + lr];
#pragma unroll
        for (int rr = 0; rr < 4; ++rr)
          scratch[(kq * 4 + rr) * 772 + gn0 + lr] = a4[rr] + bb;
      }
    }
    __syncthreads();

    // ---- Phase D: publish k (row-major) and v^T via sc0sc1 stores; q -> LDS ----
    {
      u16* kb = kbuf + (size_t)(t & 1) * 131072;
      u16* vb = vt + (size_t)(t & 1) * 131072;
      int r = tid >> 5, c8 = (tid & 31) * 8;
      BF8 qv, kv;
#pragma unroll
      for (int j2 = 0; j2 < 8; ++j2) {
        qv.u[j2] = f2bf(scratch[r * 772 + c8 + j2]);
        kv.u[j2] = f2bf(scratch[r * 772 + 256 + c8 + j2]);
      }
      *(bf16x8*)(sqb + r * 512 + ((c8 * 2) ^ SW(r))) = qv.v;
      cstore16(kb + (size_t)(r0 + r) * 256 + c8, kv.v);
      int d = tid >> 1, h8 = (tid & 1) * 8;
      BF8 vv;
#pragma unroll
      for (int j2 = 0; j2 < 8; ++j2)
        vv.u[j2] = f2bf(scratch[(h8 + j2) * 772 + 512 + d]);
      cstore16(vb + (size_t)d * 512 + r0 + h8, vv.v);
    }

    // ---- grid barrier: __syncthreads drains each wave's stores (vmcnt0); relaxed add+spin ----
    __syncthreads();
    if (tid == 0) {
      __hip_atomic_fetch_add(ctr, 1u, __ATOMIC_RELAXED, __HIP_MEMORY_SCOPE_AGENT);
      unsigned target = 32u * (unsigned)(t + 1);
      unsigned v = 0, sp = 0;
      do {
        __builtin_amdgcn_s_sleep(1);
        v = __hip_atomic_load(ctr, __ATOMIC_RELAXED, __HIP_MEMORY_SCOPE_AGENT);
      } while (v < target && ++sp < 20000000u);
    }
    __syncthreads();
    __builtin_amdgcn_sched_barrier(0);

    // ---- Phase E: S = q @ k^T over all 512 keys (sc1 loads, 2-deep pipeline) ----
    {
      const u16* kb = kbuf + (size_t)(t & 1) * 131072;
      const u16* vb = vt + (size_t)(t & 1) * 131072;
      bf16x8 qf[8];
#pragma unroll
      for (int ks = 0; ks < 8; ++ks)
        qf[ks] = *(const bf16x8*)(sqb + lr * 512 + ((ks * 64 + (kq << 4)) ^ SW(lr)));
      const u16* bp0 = kb + (size_t)(wid * 64 + lr) * 256 + (kq << 3);
      const u16* vp0 = vb + (size_t)(wid * 32 + lr) * 512 + (kq << 3);
      f32x4 e0 = {0,0,0,0}, e1 = {0,0,0,0}, e2 = {0,0,0,0}, e3 = {0,0,0,0};
#pragma unroll
      for (int ks = 0; ks < 8; ++ks) kA[ks] = cload16(bp0 + ks * 32);            // nt0
#pragma unroll
      for (int ks = 0; ks < 8; ++ks) kB[ks] = cload16(bp0 + 4096 + ks * 32);     // nt1
      WAITV8;
#pragma unroll
      for (int ks = 0; ks < 8; ++ks) e0 = __builtin_amdgcn_mfma_f32_16x16x32_bf16(qf[ks], kA[ks], e0, 0, 0, 0);
#pragma unroll
      for (int ks = 0; ks < 8; ++ks) kA[ks] = cload16(bp0 + 8192 + ks * 32);     // nt2
      WAITV8;
#pragma unroll
      for (int ks = 0; ks < 8; ++ks) e1 = __builtin_amdgcn_mfma_f32_16x16x32_bf16(qf[ks], kB[ks], e1, 0, 0, 0);
#pragma unroll
      for (int ks = 0; ks < 8; ++ks) kB[ks] = cload16(bp0 + 12288 + ks * 32);    // nt3
      WAITV8;
#pragma unroll
      for (int ks = 0; ks < 8; ++ks) e2 = __builtin_amdgcn_mfma_f32_16x16x32_bf16(qf[ks], kA[ks], e2, 0, 0, 0);
      // pre-issue PV chunk C0 (overlaps with softmax)
#pragma unroll
      for (int ks = 0; ks < 8; ++ks) vA[ks] = cload16(vp0 + ks * 32);
      WAITV8;
#pragma unroll
      for (int ks = 0; ks < 8; ++ks) e3 = __builtin_amdgcn_mfma_f32_16x16x32_bf16(qf[ks], kB[ks], e3, 0, 0, 0);
#pragma unroll
      for (int rr = 0; rr < 4; ++rr) {
        int srow = (kq * 4 + rr) * 516 + wid * 64 + lr;
        scratch[srow] = e0[rr];
        scratch[srow + 16] = e1[rr];
        scratch[srow + 32] = e2[rr];
        scratch[srow + 48] = e3[rr];
      }
    }
    __syncthreads();

    // ---- softmax (row-parallel over 32 lanes) ----
    {
      int r = tid >> 5, l32 = tid & 31;
      float vals[16];
      float m = -3.4e38f;
#pragma unroll
      for (int j2 = 0; j2 < 16; ++j2) {
        vals[j2] = scratch[r * 516 + l32 + j2 * 32];
        m = fmaxf(m, vals[j2]);
      }
#pragma unroll
      for (int s2 = 16; s2 > 0; s2 >>= 1) m = fmaxf(m, __shfl_xor(m, s2, 32));
      float sum = 0.0f;
#pragma unroll
      for (int j2 = 0; j2 < 16; ++j2) {
        vals[j2] = __expf((vals[j2] - m) * 0.0625f);
        sum += vals[j2];
      }
#pragma unroll
      for (int s2 = 16; s2 > 0; s2 >>= 1) sum += __shfl_xor(sum, s2, 32);
      float inv = 1.0f / sum;
#pragma unroll
      for (int j2 = 0; j2 < 16; ++j2) {
        int c = l32 + j2 * 32;
        *(u16*)(spb + r * 1024 + ((c * 2) ^ SW(r))) = f2bf(vals[j2] * inv);
      }
    }
    __syncthreads();

    // ---- Phase F: h += P @ V (v^T, sc1 loads, 2-deep pipeline) ----
    {
      const u16* vb = vt + (size_t)(t & 1) * 131072;
      const u16* vp0 = vb + (size_t)(wid * 32 + lr) * 512 + (kq << 3);
      bf16x8 pf[16];
#pragma unroll
      for (int ks = 0; ks < 16; ++ks)
        pf[ks] = *(const bf16x8*)(spb + lr * 1024 + ((ks * 64 + (kq << 4)) ^ SW(lr)));
      f32x4 f0 = {0,0,0,0}, f1 = {0,0,0,0};
#pragma unroll
      for (int ks = 0; ks < 8; ++ks) vB[ks] = cload16(vp0 + 256 + ks * 32);      // C1: nt0 ks8-15
      WAITV8;
#pragma unroll
      for (int ks = 0; ks < 8; ++ks) f0 = __builtin_amdgcn_mfma_f32_16x16x32_bf16(pf[ks], vA[ks], f0, 0, 0, 0);
#pragma unroll
      for (int ks = 0; ks < 8; ++ks) vA[ks] = cload16(vp0 + 8192 + ks * 32);     // C2: nt1 ks0-7
      WAITV8;
#pragma unroll
      for (int ks = 0; ks < 8; ++ks) f0 = __builtin_amdgcn_mfma_f32_16x16x32_bf16(pf[8 + ks], vB[ks], f0, 0, 0, 0);
#pragma unroll
      for (int ks = 0; ks < 8; ++ks) vB[ks] = cload16(vp0 + 8448 + ks * 32);     // C3: nt1 ks8-15
      WAITV8;
#pragma unroll
      for (int ks = 0; ks < 8; ++ks) f1 = __builtin_amdgcn_mfma_f32_16x16x32_bf16(pf[ks], vA[ks], f1, 0, 0, 0);
      WAITV0;
#pragma unroll
      for (int ks = 0; ks < 8; ++ks) f1 = __builtin_amdgcn_mfma_f32_16x16x32_bf16(pf[8 + ks], vB[ks], f1, 0, 0, 0);
      // h update: nt=0 -> f0 (d0=wid*32), nt=1 -> f1 (d0=wid*32+16)
#pragma unroll
      for (int rr = 0; rr < 4; ++rr) {
        int row = kq * 4 + rr;
        int col0 = wid * 32 + lr;
        int idx0 = row * 256 + col0;
        float hn0 = sh[idx0] + f0[rr];
        sh[idx0] = hn0;
        sosum[idx0] += hn0;
        *(u16*)(shb + row * 512 + ((col0 * 2) ^ SW(row))) = f2bf(hn0);
        int col1 = col0 + 16;
        int idx1 = row * 256 + col1;
        float hn1 = sh[idx1] + f1[rr];
        sh[idx1] = hn1;
        sosum[idx1] += hn1;
        *(u16*)(shb + row * 512 + ((col1 * 2) ^ SW(row))) = f2bf(hn1);
      }
    }
    __syncthreads();
  }

  // ---- tail: out = (osum/256) @ Wout^T + bout ----
  {
    int r = tid >> 5, c8 = (tid & 31) * 8;
    BF8 ov;
#pragma unroll
    for (int j2 = 0; j2 < 8; ++j2)
      ov.u[j2] = f2bf(sosum[r * 256 + c8 + j2] * (1.0f / 256.0f));
    *(bf16x8*)(shb + r * 512 + ((c8 * 2) ^ SW(r))) = ov.v;
  }
  __syncthreads();
  {
    bf16x8 of[8];
#pragma unroll
    for (int ks = 0; ks < 8; ++ks)
      of[ks] = *(const bf16x8*)(shb + lr * 512 + ((ks * 64 + (kq << 4)) ^ SW(lr)));
#pragma unroll
    for (int nt = 0; nt < 2; ++nt) {
      const int gn = wid * 32 + nt * 16 + lr;
      const u16* bp = WoutB + (size_t)gn * 256 + (kq << 3);
      f32x4 a4 = {0.0f, 0.0f, 0.0f, 0.0f};
#pragma unroll
      for (int ks = 0; ks < 8; ++ks)
        a4 = __builtin_amdgcn_mfma_f32_16x16x32_bf16(of[ks], *(const bf16x8*)(bp + ks * 32), a4, 0, 0, 0);
      float bb = bout[gn];
#pragma unroll
      for (int rr = 0; rr < 4; ++rr)
        dout[(size_t)(r0 + kq * 4 + rr) * 256 + gn] = a4[rr] + bb;
    }
  }
}

extern "C" void kernel_launch(void* const* d_in, const int* in_sizes, int n_in,
                              void* d_out, int out_size, void* d_ws, size_t ws_size,
                              hipStream_t stream) {
  (void)in_sizes; (void)n_in; (void)out_size; (void)ws_size;
  const float* state = (const float*)d_in[0];
  const float* actions = (const float*)d_in[1];
  const float* h0 = (const float*)d_in[2];
  const float* c0 = (const float*)d_in[3];
  const float* w0 = (const float*)d_in[4];
  const float* b0 = (const float*)d_in[5];
  const float* w1 = (const float*)d_in[6];
  const float* b1 = (const float*)d_in[7];
  const float* w2 = (const float*)d_in[8];
  const float* b2 = (const float*)d_in[9];
  const float* w3 = (const float*)d_in[10];
  const float* b3 = (const float*)d_in[11];
  const float* wih = (const float*)d_in[12];
  const float* whh = (const float*)d_in[13];
  const float* bih = (const float*)d_in[14];
  const float* bhh = (const float*)d_in[15];
  const float* wq = (const float*)d_in[16];
  const float* bq = (const float*)d_in[17];
  const float* wk = (const float*)d_in[18];
  const float* bk = (const float*)d_in[19];
  const float* wv = (const float*)d_in[20];
  const float* bv = (const float*)d_in[21];
  const float* wout = (const float*)d_in[22];
  const float* bout = (const float*)d_in[23];

  char* ws = (char*)d_ws;
  size_t off = 0;
  auto take = [&](size_t bytes) {
    off = (off + 255) & ~(size_t)255;
    char* p = ws + off;
    off += bytes;
    return p;
  };
  u16* Xpad  = (u16*)take(131072UL * 192 * 2);
  u16* ping  = (u16*)take(32768UL * 512 * 2);
  u16* pong  = (u16*)take(32768UL * 512 * 2);
  u16* X4    = (u16*)take(131072UL * 256 * 2);
  u16* W0p   = (u16*)take(512UL * 192 * 2);
  u16* W1b   = (u16*)take(512UL * 512 * 2);
  u16* W2b   = (u16*)take(512UL * 512 * 2);
  u16* W3b   = (u16*)take(256UL * 512 * 2);
  u16* Wcat  = (u16*)take(1024UL * 512 * 2);
  u16* Wqkv  = (u16*)take(768UL * 256 * 2);
  u16* WoutB = (u16*)take(256UL * 256 * 2);
  float* bg   = (float*)take(1024UL * 4);
  float* bqkvp = (float*)take(768UL * 4);
  u16* kbuf  = (u16*)take(2UL * 512 * 256 * 2);
  u16* vtb   = (u16*)take(2UL * 256 * 512 * 2);
  unsigned* ctr = (unsigned*)take(256);

  hipMemsetAsync(ctr, 0, 256, stream);
  seqenc_prep<<<2048, 256, 0, stream>>>(state, actions, w0, w1, w2, w3, wih, whh, bih, bhh,
                                        wq, wk, wv, bq, bk, bv, wout,
                                        Xpad, Wcat, Wqkv, W0p, W1b, W2b, W3b, WoutB, bg, bqkvp);
  const int CM = 32768;
  for (int c = 0; c < 4; ++c) {
    const u16* a0 = Xpad + (size_t)c * CM * 192;
    u16* x4c = X4 + (size_t)c * CM * 256;
    seqenc_gemm<<<dim3(CM / 128, 4), 256, 0, stream>>>(a0, W0p, b0, ping, 192, 512, 1);
    seqenc_gemm<<<dim3(CM / 128, 4), 256, 0, stream>>>(ping, W1b, b1, pong, 512, 512, 1);
    seqenc_gemm<<<dim3(CM / 128, 4), 256, 0, stream>>>(pong, W2b, b2, ping, 512, 512, 1);
    seqenc_gemm<<<dim3(CM / 128, 2), 256, 0, stream>>>(ping, W3b, b3, x4c, 512, 256, 0);
  }
  seqenc_recurrent<<<32, 512, 0, stream>>>(X4, Wcat, bg, Wqkv, bqkvp, kbuf, vtb,
                                           WoutB, bout, h0, c0, (float*)d_out, ctr);
}

// Round 5
// 20648.270 us; speedup vs baseline: 1.1668x; 1.0196x over previous
//
#include <hip/hip_runtime.h>

typedef unsigned short u16;
typedef unsigned int u32;
typedef unsigned long long u64;
typedef __attribute__((ext_vector_type(8))) short bf16x8;
typedef __attribute__((ext_vector_type(4))) float f32x4;

#define SW(r) (((r) & 7) << 4)

__device__ __forceinline__ u16 f2bf(float f) {
  u32 x = __float_as_uint(f);
  x += 0x7fffu + ((x >> 16) & 1u);
  return (u16)(x >> 16);
}

union BF8 { bf16x8 v; u16 u[8]; };

__device__ __forceinline__ void gload_lds16(const void* g, void* l) {
  __builtin_amdgcn_global_load_lds(
      (const __attribute__((address_space(1))) u32*)g,
      (__attribute__((address_space(3))) u32*)l, 16, 0, 0);
}

// write-through 16B store (visible at L3 once vmcnt drains; L2 never dirty)
__device__ __forceinline__ void cstore16(u16* p, bf16x8 v) {
  asm volatile("global_store_dwordx4 %0, %1, off sc0 sc1" :: "v"(p), "v"(v) : "memory");
}

__device__ __forceinline__ float fsigmoid(float x) { return 1.0f / (1.0f + __expf(-x)); }
__device__ __forceinline__ float ftanh(float x) {
  float a = fabsf(x);
  float t = __expf(-2.0f * a);
  float r = (1.0f - t) / (1.0f + t);
  return x < 0.0f ? -r : r;
}

// ---------------- prep: bf16 weight packs ----------------
__global__ void seqenc_prep_w(
    const float* __restrict__ w0, const float* __restrict__ w1,
    const float* __restrict__ w2, const float* __restrict__ w3,
    const float* __restrict__ wih, const float* __restrict__ whh,
    const float* __restrict__ bih, const float* __restrict__ bhh,
    const float* __restrict__ wq, const float* __restrict__ wk, const float* __restrict__ wv,
    const float* __restrict__ bq, const float* __restrict__ bk, const float* __restrict__ bv,
    const float* __restrict__ wout,
    u16* __restrict__ Wcat, u16* __restrict__ Wqkv,
    u16* __restrict__ W0p, u16* __restrict__ W1b, u16* __restrict__ W2b,
    u16* __restrict__ W3b, u16* __restrict__ WoutB,
    float* __restrict__ bg, float* __restrict__ bqkv)
{
  const long NC = 524288L, NQ = 196608L, N0P = 98304L;
  const long N1 = 262144L, N2 = 262144L, N3 = 131072L, NO = 65536L;
  const long NBG = 1024L, NBQ = 768L;
  const long TOT = NC + NQ + N0P + N1 + N2 + N3 + NO + NBG + NBQ;
  for (long i = (long)blockIdx.x * blockDim.x + threadIdx.x; i < TOT;
       i += (long)gridDim.x * blockDim.x) {
    long j = i;
    if (j < NC) {  // Wcat[1024][512] = [w_ih | w_hh]
      long n = j >> 9, k = j & 511;
      float v = (k < 256) ? wih[n * 256 + k] : whh[n * 256 + (k - 256)];
      Wcat[j] = f2bf(v); continue;
    }
    j -= NC;
    if (j < NQ) {  // Wqkv[768][256]
      long n = j >> 8, k = j & 255;
      float v = (n < 256) ? wq[n * 256 + k] : (n < 512) ? wk[(n - 256) * 256 + k]
                                                        : wv[(n - 512) * 256 + k];
      Wqkv[j] = f2bf(v); continue;
    }
    j -= NQ;
    if (j < N0P) {  // W0p[512][192] zero-padded
      long n = j / 192, k = j - n * 192;
      W0p[j] = f2bf(k < 160 ? w0[n * 160 + k] : 0.0f); continue;
    }
    j -= N0P;
    if (j < N1) { W1b[j] = f2bf(w1[j]); continue; }
    j -= N1;
    if (j < N2) { W2b[j] = f2bf(w2[j]); continue; }
    j -= N2;
    if (j < N3) { W3b[j] = f2bf(w3[j]); continue; }
    j -= N3;
    if (j < NO) { WoutB[j] = f2bf(wout[j]); continue; }
    j -= NO;
    if (j < NBG) { bg[j] = bih[j] + bhh[j]; continue; }
    j -= NBG;
    bqkv[j] = (j < 256) ? bq[j] : (j < 512) ? bk[j - 256] : bv[j - 512];
  }
}

// ---------------- prep: per-chunk padded concat input (t in [t0, t0+64)) ----------------
__global__ void seqenc_prep_x(
    const float* __restrict__ state, const float* __restrict__ actions,
    u16* __restrict__ XpadC, int t0)
{
  const int TOT = 32768 * 192;
  for (int i = blockIdx.x * blockDim.x + threadIdx.x; i < TOT;
       i += gridDim.x * blockDim.x) {
    int row = i / 192, col = i - row * 192;
    int tl = row >> 9, r = row & 511;
    int t = t0 + tl;
    int b = r >> 3, a = r & 7;
    float v = 0.0f;
    if (col < 128) v = state[((size_t)(b * 256 + t)) * 128 + col];
    else if (col < 160) v = actions[(((size_t)(b * 256 + t)) * 8 + a) * 32 + (col - 128)];
    XpadC[i] = f2bf(v);
  }
}

// ---------------- MLP GEMM: C[M][N] = act(A[M][K] @ B[N][K]^T + bias) ----------------
__global__ __launch_bounds__(256) void seqenc_gemm(
    const u16* __restrict__ A, const u16* __restrict__ B,
    const float* __restrict__ bias, u16* __restrict__ C,
    int K, int N, int relu)
{
  __shared__ char As[16384];
  __shared__ char Bs[16384];
  const int tid = threadIdx.x;
  const int m0 = blockIdx.x * 128, n0 = blockIdx.y * 128;
  const int wid = tid >> 6, lane = tid & 63;
  const int wm = (wid >> 1) * 64, wn = (wid & 1) * 64;
  const int lr = lane & 15, kq = lane >> 4;
  f32x4 acc[4][4] = {};
  for (int kt = 0; kt < K; kt += 64) {
#pragma unroll
    for (int i2 = 0; i2 < 4; ++i2) {
      int q = i2 * 256 + tid;
      int r = q >> 3, cb = (q & 7) << 4;
      int scb = cb ^ SW(r);
      gload_lds16(A + (size_t)(m0 + r) * K + kt + (scb >> 1), As + q * 16);
      gload_lds16(B + (size_t)(n0 + r) * K + kt + (scb >> 1), Bs + q * 16);
    }
    __syncthreads();
#pragma unroll
    for (int ks = 0; ks < 2; ++ks) {
      bf16x8 af[4], bfr[4];
      int kb = ks * 64 + (kq << 4);
#pragma unroll
      for (int tt = 0; tt < 4; ++tt) {
        int ra = wm + tt * 16 + lr;
        af[tt] = *(const bf16x8*)(As + ra * 128 + (kb ^ SW(ra)));
        int rb = wn + tt * 16 + lr;
        bfr[tt] = *(const bf16x8*)(Bs + rb * 128 + (kb ^ SW(rb)));
      }
#pragma unroll
      for (int mt = 0; mt < 4; ++mt)
#pragma unroll
        for (int nt = 0; nt < 4; ++nt)
          acc[mt][nt] = __builtin_amdgcn_mfma_f32_16x16x32_bf16(af[mt], bfr[nt], acc[mt][nt], 0, 0, 0);
    }
    __syncthreads();
  }
#pragma unroll
  for (int mt = 0; mt < 4; ++mt) {
#pragma unroll
    for (int nt = 0; nt < 4; ++nt) {
      int gn = n0 + wn + nt * 16 + lr;
      float bv = bias[gn];
#pragma unroll
      for (int rr = 0; rr < 4; ++rr) {
        int gm = m0 + wm + mt * 16 + (kq << 2) + rr;
        float v = acc[mt][nt][rr] + bv;
        if (relu) v = fmaxf(v, 0.0f);
        C[(size_t)gm * N + gn] = f2bf(v);
      }
    }
  }
}

// ---------------- persistent recurrent kernel: 32 WGs x 512 thr, 16 rows each ----------------
// k/v transport: 64-slot ring + write-through sc0sc1 stores + PLAIN cached loads.
// Within a wrap window, each ring address is written (drained at the grid barrier)
// strictly before its unique read. At each wrap (t % 64 == 0, incl. t=0 for replay
// staleness) an agent-acquire fence invalidates L2 so reused addresses refetch from L3.
__global__ __launch_bounds__(512) void seqenc_recurrent(
    const u16* __restrict__ X4, const u16* __restrict__ Wcat, const float* __restrict__ bg,
    const u16* __restrict__ Wqkv, const float* __restrict__ bqkv,
    u16* kbuf, u16* vt,
    const u16* __restrict__ WoutB, const float* __restrict__ bout,
    const float* __restrict__ h0g, const float* __restrict__ c0g,
    float* __restrict__ dout, unsigned* ctr)
{
  __shared__ float sc[16 * 256];       // c state (f32)
  __shared__ float sh[16 * 256];       // h state (f32)
  __shared__ float sosum[16 * 256];    // sum over t of h_post
  __shared__ char shb[16 * 512];       // h bf16, XOR-swizzled
  __shared__ char sqb[16 * 512];       // q bf16, XOR-swizzled
  __shared__ char spb[16 * 1024];      // P bf16, XOR-swizzled
  __shared__ float scratch[16 * 1028]; // gates / qkv / S staging

  const int tid = threadIdx.x;
  const int lane = tid & 63, wid = tid >> 6;
  const int lr = lane & 15, kq = lane >> 4;
  const int r0 = blockIdx.x * 16;

  {
    int r = tid >> 5, c8 = (tid & 31) * 8;
    BF8 hv;
#pragma unroll
    for (int j2 = 0; j2 < 8; ++j2) {
      float h = h0g[(size_t)(r0 + r) * 256 + c8 + j2];
      float c = c0g[(size_t)(r0 + r) * 256 + c8 + j2];
      sh[r * 256 + c8 + j2] = h;
      sc[r * 256 + c8 + j2] = c;
      sosum[r * 256 + c8 + j2] = 0.0f;
      hv.u[j2] = f2bf(h);
    }
    *(bf16x8*)(shb + r * 512 + ((c8 * 2) ^ SW(r))) = hv.v;
  }
  __syncthreads();

  for (int t = 0; t < 256; ++t) {
    const int slot = t & 63;
    // ---- Phase A: gates = [x_t | h] @ Wcat^T + bg  (K=512, N=1024) ----
    {
      bf16x8 xf[8], hf[8];
#pragma unroll
      for (int ks = 0; ks < 8; ++ks) {
        xf[ks] = *(const bf16x8*)(X4 + (size_t)((t << 9) + r0 + lr) * 256 + ks * 32 + (kq << 3));
        hf[ks] = *(const bf16x8*)(shb + lr * 512 + ((ks * 64 + (kq << 4)) ^ SW(lr)));
      }
#pragma unroll
      for (int nt = 0; nt < 8; ++nt) {
        const int gn0 = wid * 128 + nt * 16;
        const u16* bp = Wcat + (size_t)(gn0 + lr) * 512 + (kq << 3);
        f32x4 a4 = {0.0f, 0.0f, 0.0f, 0.0f};
#pragma unroll
        for (int ks = 0; ks < 16; ++ks) {
          bf16x8 bw = *(const bf16x8*)(bp + ks * 32);
          a4 = __builtin_amdgcn_mfma_f32_16x16x32_bf16(ks < 8 ? xf[ks] : hf[ks - 8], bw, a4, 0, 0, 0);
        }
        float bb = bg[gn0 + lr];
#pragma unroll
        for (int rr = 0; rr < 4; ++rr)
          scratch[(kq * 4 + rr) * 1028 + gn0 + lr] = a4[rr] + bb;
      }
    }
    __syncthreads();

    // ---- Phase B: LSTM pointwise update ----
    {
      int r = tid >> 5, c8 = (tid & 31) * 8;
      BF8 hv;
#pragma unroll
      for (int j2 = 0; j2 < 8; ++j2) {
        int c = c8 + j2;
        float iv = fsigmoid(scratch[r * 1028 + c]);
        float fv = fsigmoid(scratch[r * 1028 + 256 + c]);
        float gv = ftanh(scratch[r * 1028 + 512 + c]);
        float ov = fsigmoid(scratch[r * 1028 + 768 + c]);
        float cn = fv * sc[r * 256 + c] + iv * gv;
        float hn = ov * ftanh(cn);
        sc[r * 256 + c] = cn;
        sh[r * 256 + c] = hn;
        hv.u[j2] = f2bf(hn);
      }
      *(bf16x8*)(shb + r * 512 + ((c8 * 2) ^ SW(r))) = hv.v;
    }
    __syncthreads();

    // ---- Phase C: qkv = h_pre @ Wqkv^T + bqkv  (K=256, N=768) ----
    {
      bf16x8 hp[8];
#pragma unroll
      for (int ks = 0; ks < 8; ++ks)
        hp[ks] = *(const bf16x8*)(shb + lr * 512 + ((ks * 64 + (kq << 4)) ^ SW(lr)));
#pragma unroll
      for (int nt = 0; nt < 6; ++nt) {
        const int gn0 = wid * 96 + nt * 16;
        const u16* bp = Wqkv + (size_t)(gn0 + lr) * 256 + (kq << 3);
        f32x4 a4 = {0.0f, 0.0f, 0.0f, 0.0f};
#pragma unroll
        for (int ks = 0; ks < 8; ++ks)
          a4 = __builtin_amdgcn_mfma_f32_16x16x32_bf16(hp[ks], *(const bf16x8*)(bp + ks * 32), a4, 0, 0, 0);
        float bb = bqkv[gn0 + lr];
#pragma unroll
        for (int rr = 0; rr < 4; ++rr)
          scratch[(kq * 4 + rr) * 772 + gn0 + lr] = a4[rr] + bb;
      }
    }
    __syncthreads();

    // ---- Phase D: publish k (row-major) and v^T to ring slot; q -> LDS ----
    {
      u16* kb = kbuf + (size_t)slot * 131072;
      u16* vb = vt + (size_t)slot * 131072;
      int r = tid >> 5, c8 = (tid & 31) * 8;
      BF8 qv, kv;
#pragma unroll
      for (int j2 = 0; j2 < 8; ++j2) {
        qv.u[j2] = f2bf(scratch[r * 772 + c8 + j2]);
        kv.u[j2] = f2bf(scratch[r * 772 + 256 + c8 + j2]);
      }
      *(bf16x8*)(sqb + r * 512 + ((c8 * 2) ^ SW(r))) = qv.v;
      cstore16(kb + (size_t)(r0 + r) * 256 + c8, kv.v);
      int d = tid >> 1, h8 = (tid & 1) * 8;
      BF8 vv;
#pragma unroll
      for (int j2 = 0; j2 < 8; ++j2)
        vv.u[j2] = f2bf(scratch[(h8 + j2) * 772 + 512 + d]);
      cstore16(vb + (size_t)d * 512 + r0 + h8, vv.v);
    }

    // ---- grid barrier: __syncthreads drains this wave's stores (vmcnt0); relaxed add+spin ----
    __syncthreads();
    if (tid == 0) {
      __hip_atomic_fetch_add(ctr, 1u, __ATOMIC_RELAXED, __HIP_MEMORY_SCOPE_AGENT);
      unsigned target = 32u * (unsigned)(t + 1);
      unsigned v = 0, sp = 0;
      do {
        __builtin_amdgcn_s_sleep(1);
        v = __hip_atomic_load(ctr, __ATOMIC_RELAXED, __HIP_MEMORY_SCOPE_AGENT);
      } while (v < target && ++sp < 20000000u);
    }
    __syncthreads();
    // wrap fence: invalidate L1/L2 so reused ring addresses (and prev-replay lines)
    // refetch from the L3 coherence point. 4x per call, cheap.
    if (slot == 0) __builtin_amdgcn_fence(__ATOMIC_ACQUIRE, "agent");

    // ---- Phase E: S = q @ k^T over all 512 keys (plain cached loads from ring) ----
    {
      const u16* kb = kbuf + (size_t)slot * 131072;
      bf16x8 qf[8];
#pragma unroll
      for (int ks = 0; ks < 8; ++ks)
        qf[ks] = *(const bf16x8*)(sqb + lr * 512 + ((ks * 64 + (kq << 4)) ^ SW(lr)));
#pragma unroll
      for (int nt = 0; nt < 4; ++nt) {
        const int key0 = wid * 64 + nt * 16;
        const u16* bp = kb + (size_t)(key0 + lr) * 256 + (kq << 3);
        bf16x8 kf[8];
#pragma unroll
        for (int ks = 0; ks < 8; ++ks)
          kf[ks] = *(const bf16x8*)(bp + ks * 32);
        f32x4 a4 = {0.0f, 0.0f, 0.0f, 0.0f};
#pragma unroll
        for (int ks = 0; ks < 8; ++ks)
          a4 = __builtin_amdgcn_mfma_f32_16x16x32_bf16(qf[ks], kf[ks], a4, 0, 0, 0);
#pragma unroll
        for (int rr = 0; rr < 4; ++rr)
          scratch[(kq * 4 + rr) * 516 + key0 + lr] = a4[rr];
      }
    }
    __syncthreads();

    // ---- softmax (row-parallel over 32 lanes) ----
    {
      int r = tid >> 5, l32 = tid & 31;
      float vals[16];
      float m = -3.4e38f;
#pragma unroll
      for (int j2 = 0; j2 < 16; ++j2) {
        vals[j2] = scratch[r * 516 + l32 + j2 * 32];
        m = fmaxf(m, vals[j2]);
      }
#pragma unroll
      for (int s2 = 16; s2 > 0; s2 >>= 1) m = fmaxf(m, __shfl_xor(m, s2, 32));
      float sum = 0.0f;
#pragma unroll
      for (int j2 = 0; j2 < 16; ++j2) {
        vals[j2] = __expf((vals[j2] - m) * 0.0625f);
        sum += vals[j2];
      }
#pragma unroll
      for (int s2 = 16; s2 > 0; s2 >>= 1) sum += __shfl_xor(sum, s2, 32);
      float inv = 1.0f / sum;
#pragma unroll
      for (int j2 = 0; j2 < 16; ++j2) {
        int c = l32 + j2 * 32;
        *(u16*)(spb + r * 1024 + ((c * 2) ^ SW(r))) = f2bf(vals[j2] * inv);
      }
    }
    __syncthreads();

    // ---- Phase F: h += P @ V (v^T, plain cached loads from ring) ----
    {
      const u16* vb = vt + (size_t)slot * 131072;
      bf16x8 pf[16];
#pragma unroll
      for (int ks = 0; ks < 16; ++ks)
        pf[ks] = *(const bf16x8*)(spb + lr * 1024 + ((ks * 64 + (kq << 4)) ^ SW(lr)));
#pragma unroll
      for (int nt = 0; nt < 2; ++nt) {
        const int d0 = wid * 32 + nt * 16;
        const u16* bp = vb + (size_t)(d0 + lr) * 512 + (kq << 3);
        bf16x8 vf[16];
#pragma unroll
        for (int ks = 0; ks < 16; ++ks)
          vf[ks] = *(const bf16x8*)(bp + ks * 32);
        f32x4 a4 = {0.0f, 0.0f, 0.0f, 0.0f};
#pragma unroll
        for (int ks = 0; ks < 16; ++ks)
          a4 = __builtin_amdgcn_mfma_f32_16x16x32_bf16(pf[ks], vf[ks], a4, 0, 0, 0);
#pragma unroll
        for (int rr = 0; rr < 4; ++rr) {
          int row = kq * 4 + rr, col = d0 + lr;
          int idx = row * 256 + col;
          float hn = sh[idx] + a4[rr];
          sh[idx] = hn;
          sosum[idx] += hn;
          *(u16*)(shb + row * 512 + ((col * 2) ^ SW(row))) = f2bf(hn);
        }
      }
    }
    __syncthreads();
  }

  // ---- tail: out = (osum/256) @ Wout^T + bout ----
  {
    int r = tid >> 5, c8 = (tid & 31) * 8;
    BF8 ov;
#pragma unroll
    for (int j2 = 0; j2 < 8; ++j2)
      ov.u[j2] = f2bf(sosum[r * 256 + c8 + j2] * (1.0f / 256.0f));
    *(bf16x8*)(shb + r * 512 + ((c8 * 2) ^ SW(r))) = ov.v;
  }
  __syncthreads();
  {
    bf16x8 of[8];
#pragma unroll
    for (int ks = 0; ks < 8; ++ks)
      of[ks] = *(const bf16x8*)(shb + lr * 512 + ((ks * 64 + (kq << 4)) ^ SW(lr)));
#pragma unroll
    for (int nt = 0; nt < 2; ++nt) {
      const int gn = wid * 32 + nt * 16 + lr;
      const u16* bp = WoutB + (size_t)gn * 256 + (kq << 3);
      f32x4 a4 = {0.0f, 0.0f, 0.0f, 0.0f};
#pragma unroll
      for (int ks = 0; ks < 8; ++ks)
        a4 = __builtin_amdgcn_mfma_f32_16x16x32_bf16(of[ks], *(const bf16x8*)(bp + ks * 32), a4, 0, 0, 0);
      float bb = bout[gn];
#pragma unroll
      for (int rr = 0; rr < 4; ++rr)
        dout[(size_t)(r0 + kq * 4 + rr) * 256 + gn] = a4[rr] + bb;
    }
  }
}

extern "C" void kernel_launch(void* const* d_in, const int* in_sizes, int n_in,
                              void* d_out, int out_size, void* d_ws, size_t ws_size,
                              hipStream_t stream) {
  (void)in_sizes; (void)n_in; (void)out_size; (void)ws_size;
  const float* state = (const float*)d_in[0];
  const float* actions = (const float*)d_in[1];
  const float* h0 = (const float*)d_in[2];
  const float* c0 = (const float*)d_in[3];
  const float* w0 = (const float*)d_in[4];
  const float* b0 = (const float*)d_in[5];
  const float* w1 = (const float*)d_in[6];
  const float* b1 = (const float*)d_in[7];
  const float* w2 = (const float*)d_in[8];
  const float* b2 = (const float*)d_in[9];
  const float* w3 = (const float*)d_in[10];
  const float* b3 = (const float*)d_in[11];
  const float* wih = (const float*)d_in[12];
  const float* whh = (const float*)d_in[13];
  const float* bih = (const float*)d_in[14];
  const float* bhh = (const float*)d_in[15];
  const float* wq = (const float*)d_in[16];
  const float* bq = (const float*)d_in[17];
  const float* wk = (const float*)d_in[18];
  const float* bk = (const float*)d_in[19];
  const float* wv = (const float*)d_in[20];
  const float* bv = (const float*)d_in[21];
  const float* wout = (const float*)d_in[22];
  const float* bout = (const float*)d_in[23];

  char* ws = (char*)d_ws;
  size_t off = 0;
  auto take = [&](size_t bytes) {
    off = (off + 255) & ~(size_t)255;
    char* p = ws + off;
    off += bytes;
    return p;
  };
  u16* XpadC = (u16*)take(32768UL * 192 * 2);    // per-chunk padded input, 12.6 MB
  u16* ping  = (u16*)take(32768UL * 512 * 2);
  u16* pong  = (u16*)take(32768UL * 512 * 2);
  u16* X4    = (u16*)take(131072UL * 256 * 2);
  u16* W0p   = (u16*)take(512UL * 192 * 2);
  u16* W1b   = (u16*)take(512UL * 512 * 2);
  u16* W2b   = (u16*)take(512UL * 512 * 2);
  u16* W3b   = (u16*)take(256UL * 512 * 2);
  u16* Wcat  = (u16*)take(1024UL * 512 * 2);
  u16* Wqkv  = (u16*)take(768UL * 256 * 2);
  u16* WoutB = (u16*)take(256UL * 256 * 2);
  float* bg   = (float*)take(1024UL * 4);
  float* bqkvp = (float*)take(768UL * 4);
  u16* kbuf  = (u16*)take(64UL * 131072 * 2);    // 64-slot ring, 16.8 MB
  u16* vtb   = (u16*)take(64UL * 131072 * 2);    // 64-slot ring, 16.8 MB
  unsigned* ctr = (unsigned*)take(256);

  hipMemsetAsync(ctr, 0, 256, stream);
  seqenc_prep_w<<<1024, 256, 0, stream>>>(w0, w1, w2, w3, wih, whh, bih, bhh,
                                          wq, wk, wv, bq, bk, bv, wout,
                                          Wcat, Wqkv, W0p, W1b, W2b, W3b, WoutB, bg, bqkvp);
  const int CM = 32768;
  for (int c = 0; c < 4; ++c) {
    u16* x4c = X4 + (size_t)c * CM * 256;
    seqenc_prep_x<<<2048, 256, 0, stream>>>(state, actions, XpadC, c * 64);
    seqenc_gemm<<<dim3(CM / 128, 4), 256, 0, stream>>>(XpadC, W0p, b0, ping, 192, 512, 1);
    seqenc_gemm<<<dim3(CM / 128, 4), 256, 0, stream>>>(ping, W1b, b1, pong, 512, 512, 1);
    seqenc_gemm<<<dim3(CM / 128, 4), 256, 0, stream>>>(pong, W2b, b2, ping, 512, 512, 1);
    seqenc_gemm<<<dim3(CM / 128, 2), 256, 0, stream>>>(ping, W3b, b3, x4c, 512, 256, 0);
  }
  seqenc_recurrent<<<32, 512, 0, stream>>>(X4, Wcat, bg, Wqkv, bqkvp, kbuf, vtb,
                                           WoutB, bout, h0, c0, (float*)d_out, ctr);
}

// Round 6
// 20485.190 us; speedup vs baseline: 1.1761x; 1.0080x over previous
//
#include <hip/hip_runtime.h>

typedef unsigned short u16;
typedef unsigned int u32;
typedef unsigned long long u64;
typedef __attribute__((ext_vector_type(8))) short bf16x8;
typedef __attribute__((ext_vector_type(2))) unsigned int u32x2;
typedef __attribute__((ext_vector_type(4))) float f32x4;

#define SW(r) (((r) & 7) << 4)

__device__ __forceinline__ u16 f2bf(float f) {
  u32 x = __float_as_uint(f);
  x += 0x7fffu + ((x >> 16) & 1u);
  return (u16)(x >> 16);
}

union BF8 { bf16x8 v; u16 u[8]; };
union BF4 { u64 q; u32x2 d; u16 u[4]; };

__device__ __forceinline__ void gload_lds16(const void* g, void* l) {
  __builtin_amdgcn_global_load_lds(
      (const __attribute__((address_space(1))) u32*)g,
      (__attribute__((address_space(3))) u32*)l, 16, 0, 0);
}

// write-through stores (visible at L3 once vmcnt drains; L2 never dirty)
__device__ __forceinline__ void cstore16(u16* p, bf16x8 v) {
  asm volatile("global_store_dwordx4 %0, %1, off sc0 sc1" :: "v"(p), "v"(v) : "memory");
}
__device__ __forceinline__ void cstore8(u16* p, u32x2 v) {
  asm volatile("global_store_dwordx2 %0, %1, off sc0 sc1" :: "v"(p), "v"(v) : "memory");
}

__device__ __forceinline__ float fsigmoid(float x) { return 1.0f / (1.0f + __expf(-x)); }
__device__ __forceinline__ float ftanh(float x) {
  float a = fabsf(x);
  float t = __expf(-2.0f * a);
  float r = (1.0f - t) / (1.0f + t);
  return x < 0.0f ? -r : r;
}

// ---------------- prep: bf16 weight packs ----------------
__global__ void seqenc_prep_w(
    const float* __restrict__ w0, const float* __restrict__ w1,
    const float* __restrict__ w2, const float* __restrict__ w3,
    const float* __restrict__ wih, const float* __restrict__ whh,
    const float* __restrict__ bih, const float* __restrict__ bhh,
    const float* __restrict__ wq, const float* __restrict__ wk, const float* __restrict__ wv,
    const float* __restrict__ bq, const float* __restrict__ bk, const float* __restrict__ bv,
    const float* __restrict__ wout,
    u16* __restrict__ Wcat, u16* __restrict__ Wqkv,
    u16* __restrict__ W0p, u16* __restrict__ W1b, u16* __restrict__ W2b,
    u16* __restrict__ W3b, u16* __restrict__ WoutB,
    float* __restrict__ bg, float* __restrict__ bqkv)
{
  const long NC = 524288L, NQ = 196608L, N0P = 98304L;
  const long N1 = 262144L, N2 = 262144L, N3 = 131072L, NO = 65536L;
  const long NBG = 1024L, NBQ = 768L;
  const long TOT = NC + NQ + N0P + N1 + N2 + N3 + NO + NBG + NBQ;
  for (long i = (long)blockIdx.x * blockDim.x + threadIdx.x; i < TOT;
       i += (long)gridDim.x * blockDim.x) {
    long j = i;
    if (j < NC) {  // Wcat[1024][512] = [w_ih | w_hh]
      long n = j >> 9, k = j & 511;
      float v = (k < 256) ? wih[n * 256 + k] : whh[n * 256 + (k - 256)];
      Wcat[j] = f2bf(v); continue;
    }
    j -= NC;
    if (j < NQ) {  // Wqkv[768][256]
      long n = j >> 8, k = j & 255;
      float v = (n < 256) ? wq[n * 256 + k] : (n < 512) ? wk[(n - 256) * 256 + k]
                                                        : wv[(n - 512) * 256 + k];
      Wqkv[j] = f2bf(v); continue;
    }
    j -= NQ;
    if (j < N0P) {  // W0p[512][192] zero-padded
      long n = j / 192, k = j - n * 192;
      W0p[j] = f2bf(k < 160 ? w0[n * 160 + k] : 0.0f); continue;
    }
    j -= N0P;
    if (j < N1) { W1b[j] = f2bf(w1[j]); continue; }
    j -= N1;
    if (j < N2) { W2b[j] = f2bf(w2[j]); continue; }
    j -= N2;
    if (j < N3) { W3b[j] = f2bf(w3[j]); continue; }
    j -= N3;
    if (j < NO) { WoutB[j] = f2bf(wout[j]); continue; }
    j -= NO;
    if (j < NBG) { bg[j] = bih[j] + bhh[j]; continue; }
    j -= NBG;
    bqkv[j] = (j < 256) ? bq[j] : (j < 512) ? bk[j - 256] : bv[j - 512];
  }
}

// ---------------- prep: per-chunk padded concat input (t in [t0, t0+64)) ----------------
__global__ void seqenc_prep_x(
    const float* __restrict__ state, const float* __restrict__ actions,
    u16* __restrict__ XpadC, int t0)
{
  const int TOT = 32768 * 192;
  for (int i = blockIdx.x * blockDim.x + threadIdx.x; i < TOT;
       i += gridDim.x * blockDim.x) {
    int row = i / 192, col = i - row * 192;
    int tl = row >> 9, r = row & 511;
    int t = t0 + tl;
    int b = r >> 3, a = r & 7;
    float v = 0.0f;
    if (col < 128) v = state[((size_t)(b * 256 + t)) * 128 + col];
    else if (col < 160) v = actions[(((size_t)(b * 256 + t)) * 8 + a) * 32 + (col - 128)];
    XpadC[i] = f2bf(v);
  }
}

// ---------------- MLP GEMM: C[M][N] = act(A[M][K] @ B[N][K]^T + bias) ----------------
__global__ __launch_bounds__(256) void seqenc_gemm(
    const u16* __restrict__ A, const u16* __restrict__ B,
    const float* __restrict__ bias, u16* __restrict__ C,
    int K, int N, int relu)
{
  __shared__ char As[16384];
  __shared__ char Bs[16384];
  const int tid = threadIdx.x;
  const int m0 = blockIdx.x * 128, n0 = blockIdx.y * 128;
  const int wid = tid >> 6, lane = tid & 63;
  const int wm = (wid >> 1) * 64, wn = (wid & 1) * 64;
  const int lr = lane & 15, kq = lane >> 4;
  f32x4 acc[4][4] = {};
  for (int kt = 0; kt < K; kt += 64) {
#pragma unroll
    for (int i2 = 0; i2 < 4; ++i2) {
      int q = i2 * 256 + tid;
      int r = q >> 3, cb = (q & 7) << 4;
      int scb = cb ^ SW(r);
      gload_lds16(A + (size_t)(m0 + r) * K + kt + (scb >> 1), As + q * 16);
      gload_lds16(B + (size_t)(n0 + r) * K + kt + (scb >> 1), Bs + q * 16);
    }
    __syncthreads();
#pragma unroll
    for (int ks = 0; ks < 2; ++ks) {
      bf16x8 af[4], bfr[4];
      int kb = ks * 64 + (kq << 4);
#pragma unroll
      for (int tt = 0; tt < 4; ++tt) {
        int ra = wm + tt * 16 + lr;
        af[tt] = *(const bf16x8*)(As + ra * 128 + (kb ^ SW(ra)));
        int rb = wn + tt * 16 + lr;
        bfr[tt] = *(const bf16x8*)(Bs + rb * 128 + (kb ^ SW(rb)));
      }
#pragma unroll
      for (int mt = 0; mt < 4; ++mt)
#pragma unroll
        for (int nt = 0; nt < 4; ++nt)
          acc[mt][nt] = __builtin_amdgcn_mfma_f32_16x16x32_bf16(af[mt], bfr[nt], acc[mt][nt], 0, 0, 0);
    }
    __syncthreads();
  }
#pragma unroll
  for (int mt = 0; mt < 4; ++mt) {
#pragma unroll
    for (int nt = 0; nt < 4; ++nt) {
      int gn = n0 + wn + nt * 16 + lr;
      float bv = bias[gn];
#pragma unroll
      for (int rr = 0; rr < 4; ++rr) {
        int gm = m0 + wm + mt * 16 + (kq << 2) + rr;
        float v = acc[mt][nt][rr] + bv;
        if (relu) v = fmaxf(v, 0.0f);
        C[(size_t)gm * N + gn] = f2bf(v);
      }
    }
  }
}

// ---------------- persistent recurrent kernel: 128 WGs x 512 thr, 4 rows each ----------------
// 4x the outstanding-miss parallelism of the 32-WG version; MFMA tiles are 16-row with
// duplicated rows (lr&3), C-writes guarded to kq==0. Ring + wrap-fence logic as before.
__global__ __launch_bounds__(512) void seqenc_recurrent(
    const u16* __restrict__ X4, const u16* __restrict__ Wcat, const float* __restrict__ bg,
    const u16* __restrict__ Wqkv, const float* __restrict__ bqkv,
    u16* kbuf, u16* vt,
    const u16* __restrict__ WoutB, const float* __restrict__ bout,
    const float* __restrict__ h0g, const float* __restrict__ c0g,
    float* __restrict__ dout, unsigned* ctr)
{
  __shared__ float sc[4 * 256];        // c state (f32)
  __shared__ float sh[4 * 256];        // h state (f32)
  __shared__ float sosum[4 * 256];     // sum over t of h_post
  __shared__ char shb[4 * 512];        // h bf16, XOR-swizzled
  __shared__ char sqb[4 * 512];        // q bf16, XOR-swizzled
  __shared__ char spb[4 * 1024];       // P bf16, XOR-swizzled
  __shared__ float scratch[4 * 1028];  // gates / qkv / S staging

  const int tid = threadIdx.x;
  const int lane = tid & 63, wid = tid >> 6;
  const int lr = lane & 15, kq = lane >> 4;
  const int lrr = lr & 3;              // duplicated state-row index for A-fragments
  const int r0 = blockIdx.x * 4;

  if (tid < 256) {
    int r = tid >> 6, c4 = (tid & 63) * 4;
    BF4 hv;
#pragma unroll
    for (int j2 = 0; j2 < 4; ++j2) {
      float h = h0g[(size_t)(r0 + r) * 256 + c4 + j2];
      float c = c0g[(size_t)(r0 + r) * 256 + c4 + j2];
      sh[r * 256 + c4 + j2] = h;
      sc[r * 256 + c4 + j2] = c;
      sosum[r * 256 + c4 + j2] = 0.0f;
      hv.u[j2] = f2bf(h);
    }
    *(u64*)(shb + r * 512 + ((c4 * 2) ^ SW(r))) = hv.q;
  }
  __syncthreads();

  for (int t = 0; t < 256; ++t) {
    const int slot = t & 63;
    // ---- Phase A: gates = [x_t | h] @ Wcat^T + bg  (4 rows x 1024) ----
    {
      bf16x8 xf[8], hf[8];
#pragma unroll
      for (int ks = 0; ks < 8; ++ks) {
        xf[ks] = *(const bf16x8*)(X4 + (size_t)((t << 9) + r0 + lrr) * 256 + ks * 32 + (kq << 3));
        hf[ks] = *(const bf16x8*)(shb + lrr * 512 + ((ks * 64 + (kq << 4)) ^ SW(lrr)));
      }
#pragma unroll
      for (int nt = 0; nt < 8; ++nt) {
        const int gn0 = wid * 128 + nt * 16;
        const u16* bp = Wcat + (size_t)(gn0 + lr) * 512 + (kq << 3);
        f32x4 a4 = {0.0f, 0.0f, 0.0f, 0.0f};
#pragma unroll
        for (int ks = 0; ks < 16; ++ks) {
          bf16x8 bw = *(const bf16x8*)(bp + ks * 32);
          a4 = __builtin_amdgcn_mfma_f32_16x16x32_bf16(ks < 8 ? xf[ks] : hf[ks - 8], bw, a4, 0, 0, 0);
        }
        if (kq == 0) {
          float bb = bg[gn0 + lr];
#pragma unroll
          for (int rr = 0; rr < 4; ++rr)
            scratch[rr * 1028 + gn0 + lr] = a4[rr] + bb;
        }
      }
    }
    __syncthreads();

    // ---- Phase B: LSTM pointwise update ----
    if (tid < 256) {
      int r = tid >> 6, c4 = (tid & 63) * 4;
      BF4 hv;
#pragma unroll
      for (int j2 = 0; j2 < 4; ++j2) {
        int c = c4 + j2;
        float iv = fsigmoid(scratch[r * 1028 + c]);
        float fv = fsigmoid(scratch[r * 1028 + 256 + c]);
        float gv = ftanh(scratch[r * 1028 + 512 + c]);
        float ov = fsigmoid(scratch[r * 1028 + 768 + c]);
        float cn = fv * sc[r * 256 + c] + iv * gv;
        float hn = ov * ftanh(cn);
        sc[r * 256 + c] = cn;
        sh[r * 256 + c] = hn;
        hv.u[j2] = f2bf(hn);
      }
      *(u64*)(shb + r * 512 + ((c4 * 2) ^ SW(r))) = hv.q;
    }
    __syncthreads();

    // ---- Phase C: qkv = h_pre @ Wqkv^T + bqkv  (4 rows x 768) ----
    {
      bf16x8 hp[8];
#pragma unroll
      for (int ks = 0; ks < 8; ++ks)
        hp[ks] = *(const bf16x8*)(shb + lrr * 512 + ((ks * 64 + (kq << 4)) ^ SW(lrr)));
#pragma unroll
      for (int nt = 0; nt < 6; ++nt) {
        const int gn0 = wid * 96 + nt * 16;
        const u16* bp = Wqkv + (size_t)(gn0 + lr) * 256 + (kq << 3);
        f32x4 a4 = {0.0f, 0.0f, 0.0f, 0.0f};
#pragma unroll
        for (int ks = 0; ks < 8; ++ks)
          a4 = __builtin_amdgcn_mfma_f32_16x16x32_bf16(hp[ks], *(const bf16x8*)(bp + ks * 32), a4, 0, 0, 0);
        if (kq == 0) {
          float bb = bqkv[gn0 + lr];
#pragma unroll
          for (int rr = 0; rr < 4; ++rr)
            scratch[rr * 772 + gn0 + lr] = a4[rr] + bb;
        }
      }
    }
    __syncthreads();

    // ---- Phase D: publish k (row-major) and v^T to ring slot; q -> LDS ----
    {
      u16* kb = kbuf + (size_t)slot * 131072;
      u16* vb = vt + (size_t)slot * 131072;
      if (tid < 128) {
        int r = tid >> 5, c8 = (tid & 31) * 8;
        BF8 qv, kv;
#pragma unroll
        for (int j2 = 0; j2 < 8; ++j2) {
          qv.u[j2] = f2bf(scratch[r * 772 + c8 + j2]);
          kv.u[j2] = f2bf(scratch[r * 772 + 256 + c8 + j2]);
        }
        *(bf16x8*)(sqb + r * 512 + ((c8 * 2) ^ SW(r))) = qv.v;
        cstore16(kb + (size_t)(r0 + r) * 256 + c8, kv.v);
      }
      if (tid < 256) {
        int d = tid;
        BF4 vv;
#pragma unroll
        for (int j2 = 0; j2 < 4; ++j2)
          vv.u[j2] = f2bf(scratch[j2 * 772 + 512 + d]);
        cstore8(vb + (size_t)d * 512 + r0, vv.d);
      }
    }

    // ---- grid barrier: __syncthreads drains this wave's stores (vmcnt0); relaxed add+spin ----
    __syncthreads();
    if (tid == 0) {
      __hip_atomic_fetch_add(ctr, 1u, __ATOMIC_RELAXED, __HIP_MEMORY_SCOPE_AGENT);
      unsigned target = 128u * (unsigned)(t + 1);
      unsigned v = 0, sp = 0;
      do {
        __builtin_amdgcn_s_sleep(1);
        v = __hip_atomic_load(ctr, __ATOMIC_RELAXED, __HIP_MEMORY_SCOPE_AGENT);
      } while (v < target && ++sp < 20000000u);
    }
    __syncthreads();
    // wrap fence: invalidate L1/L2 so reused ring addresses (and prev-replay lines)
    // refetch from the L3 coherence point. 4x per call.
    if (slot == 0) __builtin_amdgcn_fence(__ATOMIC_ACQUIRE, "agent");

    // ---- Phase E: S = q @ k^T over all 512 keys (plain cached loads from ring) ----
    {
      const u16* kb = kbuf + (size_t)slot * 131072;
      bf16x8 qf[8];
#pragma unroll
      for (int ks = 0; ks < 8; ++ks)
        qf[ks] = *(const bf16x8*)(sqb + lrr * 512 + ((ks * 64 + (kq << 4)) ^ SW(lrr)));
#pragma unroll
      for (int nt = 0; nt < 4; ++nt) {
        const int key0 = wid * 64 + nt * 16;
        const u16* bp = kb + (size_t)(key0 + lr) * 256 + (kq << 3);
        bf16x8 kf[8];
#pragma unroll
        for (int ks = 0; ks < 8; ++ks)
          kf[ks] = *(const bf16x8*)(bp + ks * 32);
        f32x4 a4 = {0.0f, 0.0f, 0.0f, 0.0f};
#pragma unroll
        for (int ks = 0; ks < 8; ++ks)
          a4 = __builtin_amdgcn_mfma_f32_16x16x32_bf16(qf[ks], kf[ks], a4, 0, 0, 0);
        if (kq == 0) {
#pragma unroll
          for (int rr = 0; rr < 4; ++rr)
            scratch[rr * 516 + key0 + lr] = a4[rr];
        }
      }
    }
    __syncthreads();

    // ---- softmax: row r handled entirely by wave r (r < 4), width-64 shfl ----
    {
      int r = tid >> 6, l64 = tid & 63;
      if (r < 4) {
        float vals[8];
        float m = -3.4e38f;
#pragma unroll
        for (int j2 = 0; j2 < 8; ++j2) {
          vals[j2] = scratch[r * 516 + l64 + j2 * 64];
          m = fmaxf(m, vals[j2]);
        }
#pragma unroll
        for (int s2 = 32; s2 > 0; s2 >>= 1) m = fmaxf(m, __shfl_xor(m, s2, 64));
        float sum = 0.0f;
#pragma unroll
        for (int j2 = 0; j2 < 8; ++j2) {
          vals[j2] = __expf((vals[j2] - m) * 0.0625f);
          sum += vals[j2];
        }
#pragma unroll
        for (int s2 = 32; s2 > 0; s2 >>= 1) sum += __shfl_xor(sum, s2, 64);
        float inv = 1.0f / sum;
#pragma unroll
        for (int j2 = 0; j2 < 8; ++j2) {
          int c = l64 + j2 * 64;
          *(u16*)(spb + r * 1024 + ((c * 2) ^ SW(r))) = f2bf(vals[j2] * inv);
        }
      }
    }
    __syncthreads();

    // ---- Phase F: h += P @ V (v^T, plain cached loads from ring) ----
    {
      const u16* vb = vt + (size_t)slot * 131072;
      bf16x8 pf[16];
#pragma unroll
      for (int ks = 0; ks < 16; ++ks)
        pf[ks] = *(const bf16x8*)(spb + lrr * 1024 + ((ks * 64 + (kq << 4)) ^ SW(lrr)));
#pragma unroll
      for (int nt = 0; nt < 2; ++nt) {
        const int d0 = wid * 32 + nt * 16;
        const u16* bp = vb + (size_t)(d0 + lr) * 512 + (kq << 3);
        bf16x8 vf[16];
#pragma unroll
        for (int ks = 0; ks < 16; ++ks)
          vf[ks] = *(const bf16x8*)(bp + ks * 32);
        f32x4 a4 = {0.0f, 0.0f, 0.0f, 0.0f};
#pragma unroll
        for (int ks = 0; ks < 16; ++ks)
          a4 = __builtin_amdgcn_mfma_f32_16x16x32_bf16(pf[ks], vf[ks], a4, 0, 0, 0);
        if (kq == 0) {
#pragma unroll
          for (int rr = 0; rr < 4; ++rr) {
            int col = d0 + lr;
            int idx = rr * 256 + col;
            float hn = sh[idx] + a4[rr];
            sh[idx] = hn;
            sosum[idx] += hn;
            *(u16*)(shb + rr * 512 + ((col * 2) ^ SW(rr))) = f2bf(hn);
          }
        }
      }
    }
    __syncthreads();
  }

  // ---- tail: out = (osum/256) @ Wout^T + bout ----
  if (tid < 256) {
    int r = tid >> 6, c4 = (tid & 63) * 4;
    BF4 ov;
#pragma unroll
    for (int j2 = 0; j2 < 4; ++j2)
      ov.u[j2] = f2bf(sosum[r * 256 + c4 + j2] * (1.0f / 256.0f));
    *(u64*)(shb + r * 512 + ((c4 * 2) ^ SW(r))) = ov.q;
  }
  __syncthreads();
  {
    bf16x8 of[8];
#pragma unroll
    for (int ks = 0; ks < 8; ++ks)
      of[ks] = *(const bf16x8*)(shb + lrr * 512 + ((ks * 64 + (kq << 4)) ^ SW(lrr)));
#pragma unroll
    for (int nt = 0; nt < 2; ++nt) {
      const int gn = wid * 32 + nt * 16 + lr;
      const u16* bp = WoutB + (size_t)gn * 256 + (kq << 3);
      f32x4 a4 = {0.0f, 0.0f, 0.0f, 0.0f};
#pragma unroll
      for (int ks = 0; ks < 8; ++ks)
        a4 = __builtin_amdgcn_mfma_f32_16x16x32_bf16(of[ks], *(const bf16x8*)(bp + ks * 32), a4, 0, 0, 0);
      if (kq == 0) {
        float bb = bout[gn];
#pragma unroll
        for (int rr = 0; rr < 4; ++rr)
          dout[(size_t)(r0 + rr) * 256 + gn] = a4[rr] + bb;
      }
    }
  }
}

extern "C" void kernel_launch(void* const* d_in, const int* in_sizes, int n_in,
                              void* d_out, int out_size, void* d_ws, size_t ws_size,
                              hipStream_t stream) {
  (void)in_sizes; (void)n_in; (void)out_size; (void)ws_size;
  const float* state = (const float*)d_in[0];
  const float* actions = (const float*)d_in[1];
  const float* h0 = (const float*)d_in[2];
  const float* c0 = (const float*)d_in[3];
  const float* w0 = (const float*)d_in[4];
  const float* b0 = (const float*)d_in[5];
  const float* w1 = (const float*)d_in[6];
  const float* b1 = (const float*)d_in[7];
  const float* w2 = (const float*)d_in[8];
  const float* b2 = (const float*)d_in[9];
  const float* w3 = (const float*)d_in[10];
  const float* b3 = (const float*)d_in[11];
  const float* wih = (const float*)d_in[12];
  const float* whh = (const float*)d_in[13];
  const float* bih = (const float*)d_in[14];
  const float* bhh = (const float*)d_in[15];
  const float* wq = (const float*)d_in[16];
  const float* bq = (const float*)d_in[17];
  const float* wk = (const float*)d_in[18];
  const float* bk = (const float*)d_in[19];
  const float* wv = (const float*)d_in[20];
  const float* bv = (const float*)d_in[21];
  const float* wout = (const float*)d_in[22];
  const float* bout = (const float*)d_in[23];

  char* ws = (char*)d_ws;
  size_t off = 0;
  auto take = [&](size_t bytes) {
    off = (off + 255) & ~(size_t)255;
    char* p = ws + off;
    off += bytes;
    return p;
  };
  u16* XpadC = (u16*)take(32768UL * 192 * 2);    // per-chunk padded input, 12.6 MB
  u16* ping  = (u16*)take(32768UL * 512 * 2);
  u16* pong  = (u16*)take(32768UL * 512 * 2);
  u16* X4    = (u16*)take(131072UL * 256 * 2);
  u16* W0p   = (u16*)take(512UL * 192 * 2);
  u16* W1b   = (u16*)take(512UL * 512 * 2);
  u16* W2b   = (u16*)take(512UL * 512 * 2);
  u16* W3b   = (u16*)take(256UL * 512 * 2);
  u16* Wcat  = (u16*)take(1024UL * 512 * 2);
  u16* Wqkv  = (u16*)take(768UL * 256 * 2);
  u16* WoutB = (u16*)take(256UL * 256 * 2);
  float* bg   = (float*)take(1024UL * 4);
  float* bqkvp = (float*)take(768UL * 4);
  u16* kbuf  = (u16*)take(64UL * 131072 * 2);    // 64-slot ring, 16.8 MB
  u16* vtb   = (u16*)take(64UL * 131072 * 2);    // 64-slot ring, 16.8 MB
  unsigned* ctr = (unsigned*)take(256);

  hipMemsetAsync(ctr, 0, 256, stream);
  seqenc_prep_w<<<1024, 256, 0, stream>>>(w0, w1, w2, w3, wih, whh, bih, bhh,
                                          wq, wk, wv, bq, bk, bv, wout,
                                          Wcat, Wqkv, W0p, W1b, W2b, W3b, WoutB, bg, bqkvp);
  const int CM = 32768;
  for (int c = 0; c < 4; ++c) {
    u16* x4c = X4 + (size_t)c * CM * 256;
    seqenc_prep_x<<<2048, 256, 0, stream>>>(state, actions, XpadC, c * 64);
    seqenc_gemm<<<dim3(CM / 128, 4), 256, 0, stream>>>(XpadC, W0p, b0, ping, 192, 512, 1);
    seqenc_gemm<<<dim3(CM / 128, 4), 256, 0, stream>>>(ping, W1b, b1, pong, 512, 512, 1);
    seqenc_gemm<<<dim3(CM / 128, 4), 256, 0, stream>>>(pong, W2b, b2, ping, 512, 512, 1);
    seqenc_gemm<<<dim3(CM / 128, 2), 256, 0, stream>>>(ping, W3b, b3, x4c, 512, 256, 0);
  }
  seqenc_recurrent<<<128, 512, 0, stream>>>(X4, Wcat, bg, Wqkv, bqkvp, kbuf, vtb,
                                            WoutB, bout, h0, c0, (float*)d_out, ctr);
}

// Round 7
// 13600.014 us; speedup vs baseline: 1.7715x; 1.5063x over previous
//
#include <hip/hip_runtime.h>

typedef unsigned short u16;
typedef unsigned int u32;
typedef __attribute__((ext_vector_type(8))) short bf16x8;
typedef __attribute__((ext_vector_type(4))) float f32x4;

#define SW(r) (((r) & 7) << 4)

__device__ __forceinline__ u16 f2bf(float f) {
  u32 x = __float_as_uint(f);
  x += 0x7fffu + ((x >> 16) & 1u);
  return (u16)(x >> 16);
}
__device__ __forceinline__ float bf2f(u16 h) { return __uint_as_float(((u32)h) << 16); }

__device__ __forceinline__ void gload_lds16(const void* g, void* l) {
  __builtin_amdgcn_global_load_lds(
      (const __attribute__((address_space(1))) u32*)g,
      (__attribute__((address_space(3))) u32*)l, 16, 0, 0);
}

__device__ __forceinline__ float fsigmoid(float x) { return 1.0f / (1.0f + __expf(-x)); }
__device__ __forceinline__ float ftanh(float x) {
  float a = fabsf(x);
  float t = __expf(-2.0f * a);
  float r = (1.0f - t) / (1.0f + t);
  return x < 0.0f ? -r : r;
}

// ---------------- prep: bf16 weight packs ----------------
__global__ void seqenc_prep_w(
    const float* __restrict__ w0, const float* __restrict__ w1,
    const float* __restrict__ w2, const float* __restrict__ w3,
    const float* __restrict__ wih, const float* __restrict__ whh,
    const float* __restrict__ bih, const float* __restrict__ bhh,
    const float* __restrict__ wq, const float* __restrict__ wk, const float* __restrict__ wv,
    const float* __restrict__ bq, const float* __restrict__ bk, const float* __restrict__ bv,
    const float* __restrict__ wout,
    u16* __restrict__ Wcat, u16* __restrict__ Wqkv,
    u16* __restrict__ W0p, u16* __restrict__ W1b, u16* __restrict__ W2b,
    u16* __restrict__ W3b, u16* __restrict__ WoutB,
    float* __restrict__ bg, float* __restrict__ bqkv)
{
  const long NC = 524288L, NQ = 196608L, N0P = 98304L;
  const long N1 = 262144L, N2 = 262144L, N3 = 131072L, NO = 65536L;
  const long NBG = 1024L, NBQ = 768L;
  const long TOT = NC + NQ + N0P + N1 + N2 + N3 + NO + NBG + NBQ;
  for (long i = (long)blockIdx.x * blockDim.x + threadIdx.x; i < TOT;
       i += (long)gridDim.x * blockDim.x) {
    long j = i;
    if (j < NC) {  // Wcat[1024][512] = [w_ih | w_hh]
      long n = j >> 9, k = j & 511;
      float v = (k < 256) ? wih[n * 256 + k] : whh[n * 256 + (k - 256)];
      Wcat[j] = f2bf(v); continue;
    }
    j -= NC;
    if (j < NQ) {  // Wqkv[768][256]
      long n = j >> 8, k = j & 255;
      float v = (n < 256) ? wq[n * 256 + k] : (n < 512) ? wk[(n - 256) * 256 + k]
                                                        : wv[(n - 512) * 256 + k];
      Wqkv[j] = f2bf(v); continue;
    }
    j -= NQ;
    if (j < N0P) {  // W0p[512][192] zero-padded
      long n = j / 192, k = j - n * 192;
      W0p[j] = f2bf(k < 160 ? w0[n * 160 + k] : 0.0f); continue;
    }
    j -= N0P;
    if (j < N1) { W1b[j] = f2bf(w1[j]); continue; }
    j -= N1;
    if (j < N2) { W2b[j] = f2bf(w2[j]); continue; }
    j -= N2;
    if (j < N3) { W3b[j] = f2bf(w3[j]); continue; }
    j -= N3;
    if (j < NO) { WoutB[j] = f2bf(wout[j]); continue; }
    j -= NO;
    if (j < NBG) { bg[j] = bih[j] + bhh[j]; continue; }
    j -= NBG;
    bqkv[j] = (j < 256) ? bq[j] : (j < 512) ? bk[j - 256] : bv[j - 512];
  }
}

// ---------------- prep: per-chunk padded concat input (t in [t0, t0+64)) ----------------
__global__ void seqenc_prep_x(
    const float* __restrict__ state, const float* __restrict__ actions,
    u16* __restrict__ XpadC, int t0)
{
  const int TOT = 32768 * 192;
  for (int i = blockIdx.x * blockDim.x + threadIdx.x; i < TOT;
       i += gridDim.x * blockDim.x) {
    int row = i / 192, col = i - row * 192;
    int tl = row >> 9, r = row & 511;
    int t = t0 + tl;
    int b = r >> 3, a = r & 7;
    float v = 0.0f;
    if (col < 128) v = state[((size_t)(b * 256 + t)) * 128 + col];
    else if (col < 160) v = actions[(((size_t)(b * 256 + t)) * 8 + a) * 32 + (col - 128)];
    XpadC[i] = f2bf(v);
  }
}

// ---------------- state init: h0 -> bf16 hbuf, c0 -> f32 cbuf, osum = 0 ----------------
__global__ void seqenc_init(const float* __restrict__ h0, const float* __restrict__ c0,
                            u16* __restrict__ hbuf, float* __restrict__ cbuf,
                            float* __restrict__ osum)
{
  int i = blockIdx.x * blockDim.x + threadIdx.x;
  if (i < 512 * 256) {
    hbuf[i] = f2bf(h0[i]);
    cbuf[i] = c0[i];
    osum[i] = 0.0f;
  }
}

// ---------------- unified GEMM: C[M][N] = A[M][K] @ B[N][K]^T + bias ----------------
// A split: k < K1 from A1, k >= K1 from A2 (both row stride lda).
// mode 0: bf16 out; 1: bf16 + relu; 2: f32 out; 3: bf16 out, cols>=512 transposed to vT.
__global__ __launch_bounds__(256) void seqenc_gemm(
    const u16* __restrict__ A1, const u16* __restrict__ A2, int K1, int lda,
    const u16* __restrict__ B, const float* __restrict__ bias,
    void* __restrict__ C, int ldc, u16* __restrict__ vT,
    int K, int N, int mode)
{
  __shared__ char As[16384];
  __shared__ char Bs[16384];
  const int tid = threadIdx.x;
  const int m0 = blockIdx.x * 128, n0 = blockIdx.y * 128;
  const int wid = tid >> 6, lane = tid & 63;
  const int wm = (wid >> 1) * 64, wn = (wid & 1) * 64;
  const int lr = lane & 15, kq = lane >> 4;
  f32x4 acc[4][4] = {};
  for (int kt = 0; kt < K; kt += 64) {
    const u16* Abase = (kt < K1) ? (A1 + kt) : (A2 + (kt - K1));
#pragma unroll
    for (int i2 = 0; i2 < 4; ++i2) {
      int q = i2 * 256 + tid;
      int r = q >> 3, cb = (q & 7) << 4;
      int scb = cb ^ SW(r);
      gload_lds16(Abase + (size_t)(m0 + r) * lda + (scb >> 1), As + q * 16);
      gload_lds16(B + (size_t)(n0 + r) * K + kt + (scb >> 1), Bs + q * 16);
    }
    __syncthreads();
#pragma unroll
    for (int ks = 0; ks < 2; ++ks) {
      bf16x8 af[4], bfr[4];
      int kb = ks * 64 + (kq << 4);
#pragma unroll
      for (int tt = 0; tt < 4; ++tt) {
        int ra = wm + tt * 16 + lr;
        af[tt] = *(const bf16x8*)(As + ra * 128 + (kb ^ SW(ra)));
        int rb = wn + tt * 16 + lr;
        bfr[tt] = *(const bf16x8*)(Bs + rb * 128 + (kb ^ SW(rb)));
      }
#pragma unroll
      for (int mt = 0; mt < 4; ++mt)
#pragma unroll
        for (int nt = 0; nt < 4; ++nt)
          acc[mt][nt] = __builtin_amdgcn_mfma_f32_16x16x32_bf16(af[mt], bfr[nt], acc[mt][nt], 0, 0, 0);
    }
    __syncthreads();
  }
#pragma unroll
  for (int mt = 0; mt < 4; ++mt) {
#pragma unroll
    for (int nt = 0; nt < 4; ++nt) {
      int gn = n0 + wn + nt * 16 + lr;
      float bv = bias[gn];
#pragma unroll
      for (int rr = 0; rr < 4; ++rr) {
        int gm = m0 + wm + mt * 16 + (kq << 2) + rr;
        float v = acc[mt][nt][rr] + bv;
        if (mode == 1) v = fmaxf(v, 0.0f);
        if (mode == 2) {
          ((float*)C)[(size_t)gm * ldc + gn] = v;
        } else if (mode == 3 && gn >= 512) {
          vT[(size_t)(gn - 512) * 512 + gm] = f2bf(v);
        } else {
          ((u16*)C)[(size_t)gm * ldc + gn] = f2bf(v);
        }
      }
    }
  }
}

// ---------------- LSTM pointwise: gates f32 [512][1024] + c -> h' bf16, c' f32 ----------------
__global__ __launch_bounds__(256) void seqenc_lstm(
    const float* __restrict__ G, float* __restrict__ cbuf, u16* __restrict__ hbuf)
{
  int idx = blockIdx.x * blockDim.x + threadIdx.x;   // 128 WGs x 256 thr = 32768 = 512*64
  int r = idx >> 6, c4 = (idx & 63) * 4;
  f32x4 I = *(const f32x4*)(G + (size_t)r * 1024 + c4);
  f32x4 F = *(const f32x4*)(G + (size_t)r * 1024 + 256 + c4);
  f32x4 Gg = *(const f32x4*)(G + (size_t)r * 1024 + 512 + c4);
  f32x4 O = *(const f32x4*)(G + (size_t)r * 1024 + 768 + c4);
  f32x4 c = *(const f32x4*)(cbuf + (size_t)r * 256 + c4);
  u16 hq[4];
#pragma unroll
  for (int j = 0; j < 4; ++j) {
    float cn = fsigmoid(F[j]) * c[j] + fsigmoid(I[j]) * ftanh(Gg[j]);
    float hn = fsigmoid(O[j]) * ftanh(cn);
    c[j] = cn;
    hq[j] = f2bf(hn);
  }
  *(f32x4*)(cbuf + (size_t)r * 256 + c4) = c;
  *(unsigned long long*)(hbuf + (size_t)r * 256 + c4) =
      ((unsigned long long)hq[0]) | ((unsigned long long)hq[1] << 16) |
      ((unsigned long long)hq[2] << 32) | ((unsigned long long)hq[3] << 48);
}

// ---------------- attention: 32 WGs x 16 rows; S=qk^T, softmax, h''=h'+PV; osum += h'' ----------------
__global__ __launch_bounds__(512) void seqenc_attn(
    const u16* __restrict__ QKV, const u16* __restrict__ vT,
    u16* __restrict__ hbuf, float* __restrict__ osum)
{
  __shared__ float scratch[16 * 516];
  __shared__ char spb[16 * 1024];
  const int tid = threadIdx.x;
  const int lane = tid & 63, wid = tid >> 6;
  const int lr = lane & 15, kq = lane >> 4;
  const int r0 = blockIdx.x * 16;

  // S = q @ k^T over all 512 keys
  {
    bf16x8 qf[8];
#pragma unroll
    for (int ks = 0; ks < 8; ++ks)
      qf[ks] = *(const bf16x8*)(QKV + (size_t)(r0 + lr) * 768 + ks * 32 + (kq << 3));
#pragma unroll
    for (int nt = 0; nt < 4; ++nt) {
      const int key0 = wid * 64 + nt * 16;
      const u16* bp = QKV + (size_t)(key0 + lr) * 768 + 256 + (kq << 3);
      bf16x8 kf[8];
#pragma unroll
      for (int ks = 0; ks < 8; ++ks)
        kf[ks] = *(const bf16x8*)(bp + ks * 32);
      f32x4 a4 = {0.0f, 0.0f, 0.0f, 0.0f};
#pragma unroll
      for (int ks = 0; ks < 8; ++ks)
        a4 = __builtin_amdgcn_mfma_f32_16x16x32_bf16(qf[ks], kf[ks], a4, 0, 0, 0);
#pragma unroll
      for (int rr = 0; rr < 4; ++rr)
        scratch[(kq * 4 + rr) * 516 + key0 + lr] = a4[rr];
    }
  }
  __syncthreads();

  // softmax (row-parallel over 32 lanes)
  {
    int r = tid >> 5, l32 = tid & 31;
    float vals[16];
    float m = -3.4e38f;
#pragma unroll
    for (int j2 = 0; j2 < 16; ++j2) {
      vals[j2] = scratch[r * 516 + l32 + j2 * 32];
      m = fmaxf(m, vals[j2]);
    }
#pragma unroll
    for (int s2 = 16; s2 > 0; s2 >>= 1) m = fmaxf(m, __shfl_xor(m, s2, 32));
    float sum = 0.0f;
#pragma unroll
    for (int j2 = 0; j2 < 16; ++j2) {
      vals[j2] = __expf((vals[j2] - m) * 0.0625f);
      sum += vals[j2];
    }
#pragma unroll
    for (int s2 = 16; s2 > 0; s2 >>= 1) sum += __shfl_xor(sum, s2, 32);
    float inv = 1.0f / sum;
#pragma unroll
    for (int j2 = 0; j2 < 16; ++j2) {
      int c = l32 + j2 * 32;
      *(u16*)(spb + r * 1024 + ((c * 2) ^ SW(r))) = f2bf(vals[j2] * inv);
    }
  }
  __syncthreads();

  // h'' = h' + P @ V (via vT), osum += h''
  {
    bf16x8 pf[16];
#pragma unroll
    for (int ks = 0; ks < 16; ++ks)
      pf[ks] = *(const bf16x8*)(spb + lr * 1024 + ((ks * 64 + (kq << 4)) ^ SW(lr)));
#pragma unroll
    for (int nt = 0; nt < 2; ++nt) {
      const int d0 = wid * 32 + nt * 16;
      const u16* bp = vT + (size_t)(d0 + lr) * 512 + (kq << 3);
      bf16x8 vf[16];
#pragma unroll
      for (int ks = 0; ks < 16; ++ks)
        vf[ks] = *(const bf16x8*)(bp + ks * 32);
      f32x4 a4 = {0.0f, 0.0f, 0.0f, 0.0f};
#pragma unroll
      for (int ks = 0; ks < 16; ++ks)
        a4 = __builtin_amdgcn_mfma_f32_16x16x32_bf16(pf[ks], vf[ks], a4, 0, 0, 0);
#pragma unroll
      for (int rr = 0; rr < 4; ++rr) {
        int row = kq * 4 + rr, col = d0 + lr;
        size_t gi = (size_t)(r0 + row) * 256 + col;
        float hn = bf2f(hbuf[gi]) + a4[rr];
        hbuf[gi] = f2bf(hn);
        osum[gi] += hn;
      }
    }
  }
}

// ---------------- osum/256 -> bf16 ----------------
__global__ void seqenc_conv(const float* __restrict__ osum, u16* __restrict__ ob)
{
  int i = blockIdx.x * blockDim.x + threadIdx.x;
  if (i < 512 * 256) ob[i] = f2bf(osum[i] * (1.0f / 256.0f));
}

extern "C" void kernel_launch(void* const* d_in, const int* in_sizes, int n_in,
                              void* d_out, int out_size, void* d_ws, size_t ws_size,
                              hipStream_t stream) {
  (void)in_sizes; (void)n_in; (void)out_size; (void)ws_size;
  const float* state = (const float*)d_in[0];
  const float* actions = (const float*)d_in[1];
  const float* h0 = (const float*)d_in[2];
  const float* c0 = (const float*)d_in[3];
  const float* w0 = (const float*)d_in[4];
  const float* b0 = (const float*)d_in[5];
  const float* w1 = (const float*)d_in[6];
  const float* b1 = (const float*)d_in[7];
  const float* w2 = (const float*)d_in[8];
  const float* b2 = (const float*)d_in[9];
  const float* w3 = (const float*)d_in[10];
  const float* b3 = (const float*)d_in[11];
  const float* wih = (const float*)d_in[12];
  const float* whh = (const float*)d_in[13];
  const float* bih = (const float*)d_in[14];
  const float* bhh = (const float*)d_in[15];
  const float* wq = (const float*)d_in[16];
  const float* bq = (const float*)d_in[17];
  const float* wk = (const float*)d_in[18];
  const float* bk = (const float*)d_in[19];
  const float* wv = (const float*)d_in[20];
  const float* bv = (const float*)d_in[21];
  const float* wout = (const float*)d_in[22];
  const float* bout = (const float*)d_in[23];

  char* ws = (char*)d_ws;
  size_t off = 0;
  auto take = [&](size_t bytes) {
    off = (off + 255) & ~(size_t)255;
    char* p = ws + off;
    off += bytes;
    return p;
  };
  u16* XpadC = (u16*)take(32768UL * 192 * 2);
  u16* ping  = (u16*)take(32768UL * 512 * 2);
  u16* pong  = (u16*)take(32768UL * 512 * 2);
  u16* X4    = (u16*)take(131072UL * 256 * 2);
  u16* W0p   = (u16*)take(512UL * 192 * 2);
  u16* W1b   = (u16*)take(512UL * 512 * 2);
  u16* W2b   = (u16*)take(512UL * 512 * 2);
  u16* W3b   = (u16*)take(256UL * 512 * 2);
  u16* Wcat  = (u16*)take(1024UL * 512 * 2);
  u16* Wqkv  = (u16*)take(768UL * 256 * 2);
  u16* WoutB = (u16*)take(256UL * 256 * 2);
  float* bg    = (float*)take(1024UL * 4);
  float* bqkvp = (float*)take(768UL * 4);
  float* G     = (float*)take(512UL * 1024 * 4);   // gates f32, 2 MB
  u16* QKV   = (u16*)take(512UL * 768 * 2);        // q|k|v row-major
  u16* vT    = (u16*)take(256UL * 512 * 2);        // v transposed [d][key]
  u16* hbuf  = (u16*)take(512UL * 256 * 2);        // h (bf16)
  float* cbuf  = (float*)take(512UL * 256 * 4);    // c (f32)
  float* osum  = (float*)take(512UL * 256 * 4);    // sum of h'' over t
  u16* ob    = (u16*)take(512UL * 256 * 2);        // osum/256 bf16

  seqenc_prep_w<<<1024, 256, 0, stream>>>(w0, w1, w2, w3, wih, whh, bih, bhh,
                                          wq, wk, wv, bq, bk, bv, wout,
                                          Wcat, Wqkv, W0p, W1b, W2b, W3b, WoutB, bg, bqkvp);
  seqenc_init<<<512, 256, 0, stream>>>(h0, c0, hbuf, cbuf, osum);

  const int CM = 32768;
  for (int c = 0; c < 4; ++c) {
    u16* x4c = X4 + (size_t)c * CM * 256;
    seqenc_prep_x<<<2048, 256, 0, stream>>>(state, actions, XpadC, c * 64);
    seqenc_gemm<<<dim3(CM / 128, 4), 256, 0, stream>>>(XpadC, XpadC, 192, 192, W0p, b0, ping, 512, nullptr, 192, 512, 1);
    seqenc_gemm<<<dim3(CM / 128, 4), 256, 0, stream>>>(ping, ping, 512, 512, W1b, b1, pong, 512, nullptr, 512, 512, 1);
    seqenc_gemm<<<dim3(CM / 128, 4), 256, 0, stream>>>(pong, pong, 512, 512, W2b, b2, ping, 512, nullptr, 512, 512, 1);
    seqenc_gemm<<<dim3(CM / 128, 2), 256, 0, stream>>>(ping, ping, 512, 512, W3b, b3, x4c, 256, nullptr, 512, 256, 0);
  }

  for (int t = 0; t < 256; ++t) {
    const u16* xt = X4 + (size_t)t * 512 * 256;
    // gates = [x_t | h] @ Wcat^T + bg  -> f32 G
    seqenc_gemm<<<dim3(4, 8), 256, 0, stream>>>(xt, hbuf, 256, 256, Wcat, bg, G, 1024, nullptr, 512, 1024, 2);
    // LSTM pointwise
    seqenc_lstm<<<128, 256, 0, stream>>>(G, cbuf, hbuf);
    // qkv = h' @ Wqkv^T + bqkv -> QKV (v part transposed into vT)
    seqenc_gemm<<<dim3(4, 6), 256, 0, stream>>>(hbuf, hbuf, 256, 256, Wqkv, bqkvp, QKV, 768, vT, 256, 768, 3);
    // attention + h update + osum
    seqenc_attn<<<32, 512, 0, stream>>>(QKV, vT, hbuf, osum);
  }

  seqenc_conv<<<512, 256, 0, stream>>>(osum, ob);
  seqenc_gemm<<<dim3(4, 2), 256, 0, stream>>>(ob, ob, 256, 256, WoutB, bout, d_out, 256, nullptr, 256, 256, 2);
}

// Round 8
// 11692.541 us; speedup vs baseline: 2.0605x; 1.1631x over previous
//
#include <hip/hip_runtime.h>

typedef unsigned short u16;
typedef unsigned int u32;
typedef __attribute__((ext_vector_type(8))) short bf16x8;
typedef __attribute__((ext_vector_type(4))) float f32x4;

#define SW(r) (((r) & 7) << 4)
#define RAW_BAR() { __builtin_amdgcn_s_barrier(); __builtin_amdgcn_sched_barrier(0); }
#define WAITV(N) { asm volatile("s_waitcnt vmcnt(" #N ")" ::: "memory"); __builtin_amdgcn_sched_barrier(0); }

__device__ __forceinline__ u16 f2bf(float f) {
  u32 x = __float_as_uint(f);
  x += 0x7fffu + ((x >> 16) & 1u);
  return (u16)(x >> 16);
}
__device__ __forceinline__ float bf2f(u16 h) { return __uint_as_float(((u32)h) << 16); }

__device__ __forceinline__ void gload_lds16(const void* g, void* l) {
  __builtin_amdgcn_global_load_lds(
      (const __attribute__((address_space(1))) u32*)g,
      (__attribute__((address_space(3))) u32*)l, 16, 0, 0);
}

__device__ __forceinline__ float fsigmoid(float x) { return 1.0f / (1.0f + __expf(-x)); }
__device__ __forceinline__ float ftanh(float x) {
  float a = fabsf(x);
  float t = __expf(-2.0f * a);
  float r = (1.0f - t) / (1.0f + t);
  return x < 0.0f ? -r : r;
}

// ---------------- prep: bf16 weight packs ----------------
// WcatI: gate-interleaved layout n = (c>>4)*64 + g*16 + (c&15); k: [w_ih | w_hh]
__global__ void seqenc_prep_w(
    const float* __restrict__ w0, const float* __restrict__ w1,
    const float* __restrict__ w2, const float* __restrict__ w3,
    const float* __restrict__ wih, const float* __restrict__ whh,
    const float* __restrict__ bih, const float* __restrict__ bhh,
    const float* __restrict__ wq, const float* __restrict__ wk, const float* __restrict__ wv,
    const float* __restrict__ bq, const float* __restrict__ bk, const float* __restrict__ bv,
    const float* __restrict__ wout,
    u16* __restrict__ WcatI, u16* __restrict__ Wqkv,
    u16* __restrict__ W0p, u16* __restrict__ W1b, u16* __restrict__ W2b,
    u16* __restrict__ W3b, u16* __restrict__ WoutB,
    float* __restrict__ bgI, float* __restrict__ bqkv)
{
  const long NC = 524288L, NQ = 196608L, N0P = 98304L;
  const long N1 = 262144L, N2 = 262144L, N3 = 131072L, NO = 65536L;
  const long NBG = 1024L, NBQ = 768L;
  const long TOT = NC + NQ + N0P + N1 + N2 + N3 + NO + NBG + NBQ;
  for (long i = (long)blockIdx.x * blockDim.x + threadIdx.x; i < TOT;
       i += (long)gridDim.x * blockDim.x) {
    long j = i;
    if (j < NC) {  // WcatI[1024][512]
      long n = j >> 9, k = j & 511;
      int g = (int)((n & 63) >> 4);
      int c = (int)((n >> 6) * 16 + (n & 15));
      long orig = g * 256 + c;
      float v = (k < 256) ? wih[orig * 256 + k] : whh[orig * 256 + (k - 256)];
      WcatI[j] = f2bf(v); continue;
    }
    j -= NC;
    if (j < NQ) {  // Wqkv[768][256]
      long n = j >> 8, k = j & 255;
      float v = (n < 256) ? wq[n * 256 + k] : (n < 512) ? wk[(n - 256) * 256 + k]
                                                        : wv[(n - 512) * 256 + k];
      Wqkv[j] = f2bf(v); continue;
    }
    j -= NQ;
    if (j < N0P) {  // W0p[512][192] zero-padded
      long n = j / 192, k = j - n * 192;
      W0p[j] = f2bf(k < 160 ? w0[n * 160 + k] : 0.0f); continue;
    }
    j -= N0P;
    if (j < N1) { W1b[j] = f2bf(w1[j]); continue; }
    j -= N1;
    if (j < N2) { W2b[j] = f2bf(w2[j]); continue; }
    j -= N2;
    if (j < N3) { W3b[j] = f2bf(w3[j]); continue; }
    j -= N3;
    if (j < NO) { WoutB[j] = f2bf(wout[j]); continue; }
    j -= NO;
    if (j < NBG) {  // bgI interleaved like WcatI rows
      int g = (int)((j & 63) >> 4);
      int c = (int)((j >> 6) * 16 + (j & 15));
      long orig = g * 256 + c;
      bgI[j] = bih[orig] + bhh[orig]; continue;
    }
    j -= NBG;
    bqkv[j] = (j < 256) ? bq[j] : (j < 512) ? bk[j - 256] : bv[j - 512];
  }
}

// ---------------- prep: per-chunk padded concat input (t in [t0, t0+64)) ----------------
__global__ void seqenc_prep_x(
    const float* __restrict__ state, const float* __restrict__ actions,
    u16* __restrict__ XpadC, int t0)
{
  const int TOT = 32768 * 192;
  for (int i = blockIdx.x * blockDim.x + threadIdx.x; i < TOT;
       i += gridDim.x * blockDim.x) {
    int row = i / 192, col = i - row * 192;
    int tl = row >> 9, r = row & 511;
    int t = t0 + tl;
    int b = r >> 3, a = r & 7;
    float v = 0.0f;
    if (col < 128) v = state[((size_t)(b * 256 + t)) * 128 + col];
    else if (col < 160) v = actions[(((size_t)(b * 256 + t)) * 8 + a) * 32 + (col - 128)];
    XpadC[i] = f2bf(v);
  }
}

// ---------------- state init ----------------
__global__ void seqenc_init(const float* __restrict__ h0, const float* __restrict__ c0,
                            u16* __restrict__ hbuf, float* __restrict__ cbuf,
                            float* __restrict__ osum)
{
  int i = blockIdx.x * blockDim.x + threadIdx.x;
  if (i < 512 * 256) {
    hbuf[i] = f2bf(h0[i]);
    cbuf[i] = c0[i];
    osum[i] = 0.0f;
  }
}

// ---------------- unified GEMM (depth-2 pipelined): C = A @ B^T + bias ----------------
// mode 0: bf16 out; 1: bf16 + relu; 2: f32 out; 3: bf16 out, cols>=512 transposed to vT.
__global__ __launch_bounds__(256) void seqenc_gemm(
    const u16* __restrict__ A1, const u16* __restrict__ A2, int K1, int lda,
    const u16* __restrict__ B, const float* __restrict__ bias,
    void* __restrict__ C, int ldc, u16* __restrict__ vT,
    int K, int N, int mode)
{
  __shared__ char As[2][16384];
  __shared__ char Bs[2][16384];
  const int tid = threadIdx.x;
  const int m0 = blockIdx.x * 128, n0 = blockIdx.y * 128;
  const int wid = tid >> 6, lane = tid & 63;
  const int wm = (wid >> 1) * 64, wn = (wid & 1) * 64;
  const int lr = lane & 15, kq = lane >> 4;
  f32x4 acc[4][4] = {};

  auto stage = [&](int tk, int buf) {
    int kt = tk << 6;
    const u16* Abase = (kt < K1) ? (A1 + kt) : (A2 + (kt - K1));
#pragma unroll
    for (int i2 = 0; i2 < 4; ++i2) {
      int q = i2 * 256 + tid;
      int r = q >> 3, cb = (q & 7) << 4;
      int scb = cb ^ SW(r);
      gload_lds16(Abase + (size_t)(m0 + r) * lda + (scb >> 1), As[buf] + q * 16);
      gload_lds16(B + (size_t)(n0 + r) * K + kt + (scb >> 1), Bs[buf] + q * 16);
    }
  };

  const int NT = K >> 6;
  stage(0, 0);
  int cur = 0;
  for (int t = 0; t < NT; ++t) {
    if (t + 1 < NT) { stage(t + 1, cur ^ 1); WAITV(8); }
    else { WAITV(0); }
    RAW_BAR();
#pragma unroll
    for (int ks = 0; ks < 2; ++ks) {
      bf16x8 af[4], bfr[4];
      int kb = ks * 64 + (kq << 4);
#pragma unroll
      for (int tt = 0; tt < 4; ++tt) {
        int ra = wm + tt * 16 + lr;
        af[tt] = *(const bf16x8*)(As[cur] + ra * 128 + (kb ^ SW(ra)));
        int rb = wn + tt * 16 + lr;
        bfr[tt] = *(const bf16x8*)(Bs[cur] + rb * 128 + (kb ^ SW(rb)));
      }
#pragma unroll
      for (int mt = 0; mt < 4; ++mt)
#pragma unroll
        for (int nt = 0; nt < 4; ++nt)
          acc[mt][nt] = __builtin_amdgcn_mfma_f32_16x16x32_bf16(af[mt], bfr[nt], acc[mt][nt], 0, 0, 0);
    }
    RAW_BAR();
    cur ^= 1;
  }

#pragma unroll
  for (int mt = 0; mt < 4; ++mt) {
#pragma unroll
    for (int nt = 0; nt < 4; ++nt) {
      int gn = n0 + wn + nt * 16 + lr;
      float bv = bias[gn];
#pragma unroll
      for (int rr = 0; rr < 4; ++rr) {
        int gm = m0 + wm + mt * 16 + (kq << 2) + rr;
        float v = acc[mt][nt][rr] + bv;
        if (mode == 1) v = fmaxf(v, 0.0f);
        if (mode == 2) {
          ((float*)C)[(size_t)gm * ldc + gn] = v;
        } else if (mode == 3 && gn >= 512) {
          vT[(size_t)(gn - 512) * 512 + gm] = f2bf(v);
        } else {
          ((u16*)C)[(size_t)gm * ldc + gn] = f2bf(v);
        }
      }
    }
  }
}

// ---------------- fused gates GEMM + LSTM pointwise ----------------
// B = WcatI (gate-interleaved): thread's acc[mt][0..3] = {i,f,g,o} of cell cg.
// Reads h_{t-1} from hbuf (A2); writes h' (bf16) to hq and c' (f32) to cbuf in-place.
__global__ __launch_bounds__(256) void seqenc_gates_lstm(
    const u16* __restrict__ xt, const u16* __restrict__ hbuf,
    const u16* __restrict__ WcatI, const float* __restrict__ bgI,
    float* __restrict__ cbuf, u16* __restrict__ hq)
{
  __shared__ char As[2][16384];
  __shared__ char Bs[2][16384];
  const int tid = threadIdx.x;
  const int m0 = blockIdx.x * 128, n0 = blockIdx.y * 128;
  const int wid = tid >> 6, lane = tid & 63;
  const int wm = (wid >> 1) * 64, wn = (wid & 1) * 64;
  const int lr = lane & 15, kq = lane >> 4;
  const int K = 512, K1 = 256, lda = 256;
  f32x4 acc[4][4] = {};

  auto stage = [&](int tk, int buf) {
    int kt = tk << 6;
    const u16* Abase = (kt < K1) ? (xt + kt) : (hbuf + (kt - K1));
#pragma unroll
    for (int i2 = 0; i2 < 4; ++i2) {
      int q = i2 * 256 + tid;
      int r = q >> 3, cb = (q & 7) << 4;
      int scb = cb ^ SW(r);
      gload_lds16(Abase + (size_t)(m0 + r) * lda + (scb >> 1), As[buf] + q * 16);
      gload_lds16(WcatI + (size_t)(n0 + r) * K + kt + (scb >> 1), Bs[buf] + q * 16);
    }
  };

  const int NT = 8;
  stage(0, 0);
  int cur = 0;
  for (int t = 0; t < NT; ++t) {
    if (t + 1 < NT) { stage(t + 1, cur ^ 1); WAITV(8); }
    else { WAITV(0); }
    RAW_BAR();
#pragma unroll
    for (int ks = 0; ks < 2; ++ks) {
      bf16x8 af[4], bfr[4];
      int kb = ks * 64 + (kq << 4);
#pragma unroll
      for (int tt = 0; tt < 4; ++tt) {
        int ra = wm + tt * 16 + lr;
        af[tt] = *(const bf16x8*)(As[cur] + ra * 128 + (kb ^ SW(ra)));
        int rb = wn + tt * 16 + lr;
        bfr[tt] = *(const bf16x8*)(Bs[cur] + rb * 128 + (kb ^ SW(rb)));
      }
#pragma unroll
      for (int mt = 0; mt < 4; ++mt)
#pragma unroll
        for (int nt = 0; nt < 4; ++nt)
          acc[mt][nt] = __builtin_amdgcn_mfma_f32_16x16x32_bf16(af[mt], bfr[nt], acc[mt][nt], 0, 0, 0);
    }
    RAW_BAR();
    cur ^= 1;
  }

  // LSTM epilogue: acc[mt][g][rr] are the 4 gates of cell cg for row gm.
  const int nb = n0 + wn;
  const int cg = (nb >> 6) * 16 + lr;
  const float bi = bgI[nb + lr];
  const float bf = bgI[nb + 16 + lr];
  const float bgv = bgI[nb + 32 + lr];
  const float bo = bgI[nb + 48 + lr];
#pragma unroll
  for (int mt = 0; mt < 4; ++mt) {
#pragma unroll
    for (int rr = 0; rr < 4; ++rr) {
      int gm = m0 + wm + mt * 16 + (kq << 2) + rr;
      size_t gi = (size_t)gm * 256 + cg;
      float i_ = fsigmoid(acc[mt][0][rr] + bi);
      float f_ = fsigmoid(acc[mt][1][rr] + bf);
      float g_ = ftanh(acc[mt][2][rr] + bgv);
      float o_ = fsigmoid(acc[mt][3][rr] + bo);
      float cn = f_ * cbuf[gi] + i_ * g_;
      float hn = o_ * ftanh(cn);
      cbuf[gi] = cn;
      hq[gi] = f2bf(hn);
    }
  }
}

// ---------------- attention: 32 WGs x 16 rows; h''=h'+PV; osum += h'' ----------------
__global__ __launch_bounds__(512) void seqenc_attn(
    const u16* __restrict__ QKV, const u16* __restrict__ vT,
    const u16* __restrict__ hq, u16* __restrict__ hbuf, float* __restrict__ osum)
{
  __shared__ float scratch[16 * 516];
  __shared__ char spb[16 * 1024];
  const int tid = threadIdx.x;
  const int lane = tid & 63, wid = tid >> 6;
  const int lr = lane & 15, kq = lane >> 4;
  const int r0 = blockIdx.x * 16;

  {
    bf16x8 qf[8];
#pragma unroll
    for (int ks = 0; ks < 8; ++ks)
      qf[ks] = *(const bf16x8*)(QKV + (size_t)(r0 + lr) * 768 + ks * 32 + (kq << 3));
#pragma unroll
    for (int nt = 0; nt < 4; ++nt) {
      const int key0 = wid * 64 + nt * 16;
      const u16* bp = QKV + (size_t)(key0 + lr) * 768 + 256 + (kq << 3);
      bf16x8 kf[8];
#pragma unroll
      for (int ks = 0; ks < 8; ++ks)
        kf[ks] = *(const bf16x8*)(bp + ks * 32);
      f32x4 a4 = {0.0f, 0.0f, 0.0f, 0.0f};
#pragma unroll
      for (int ks = 0; ks < 8; ++ks)
        a4 = __builtin_amdgcn_mfma_f32_16x16x32_bf16(qf[ks], kf[ks], a4, 0, 0, 0);
#pragma unroll
      for (int rr = 0; rr < 4; ++rr)
        scratch[(kq * 4 + rr) * 516 + key0 + lr] = a4[rr];
    }
  }
  __syncthreads();

  {
    int r = tid >> 5, l32 = tid & 31;
    float vals[16];
    float m = -3.4e38f;
#pragma unroll
    for (int j2 = 0; j2 < 16; ++j2) {
      vals[j2] = scratch[r * 516 + l32 + j2 * 32];
      m = fmaxf(m, vals[j2]);
    }
#pragma unroll
    for (int s2 = 16; s2 > 0; s2 >>= 1) m = fmaxf(m, __shfl_xor(m, s2, 32));
    float sum = 0.0f;
#pragma unroll
    for (int j2 = 0; j2 < 16; ++j2) {
      vals[j2] = __expf((vals[j2] - m) * 0.0625f);
      sum += vals[j2];
    }
#pragma unroll
    for (int s2 = 16; s2 > 0; s2 >>= 1) sum += __shfl_xor(sum, s2, 32);
    float inv = 1.0f / sum;
#pragma unroll
    for (int j2 = 0; j2 < 16; ++j2) {
      int c = l32 + j2 * 32;
      *(u16*)(spb + r * 1024 + ((c * 2) ^ SW(r))) = f2bf(vals[j2] * inv);
    }
  }
  __syncthreads();

  {
    bf16x8 pf[16];
#pragma unroll
    for (int ks = 0; ks < 16; ++ks)
      pf[ks] = *(const bf16x8*)(spb + lr * 1024 + ((ks * 64 + (kq << 4)) ^ SW(lr)));
#pragma unroll
    for (int nt = 0; nt < 2; ++nt) {
      const int d0 = wid * 32 + nt * 16;
      const u16* bp = vT + (size_t)(d0 + lr) * 512 + (kq << 3);
      bf16x8 vf[16];
#pragma unroll
      for (int ks = 0; ks < 16; ++ks)
        vf[ks] = *(const bf16x8*)(bp + ks * 32);
      f32x4 a4 = {0.0f, 0.0f, 0.0f, 0.0f};
#pragma unroll
      for (int ks = 0; ks < 16; ++ks)
        a4 = __builtin_amdgcn_mfma_f32_16x16x32_bf16(pf[ks], vf[ks], a4, 0, 0, 0);
#pragma unroll
      for (int rr = 0; rr < 4; ++rr) {
        int row = kq * 4 + rr, col = d0 + lr;
        size_t gi = (size_t)(r0 + row) * 256 + col;
        float hn = bf2f(hq[gi]) + a4[rr];
        hbuf[gi] = f2bf(hn);
        osum[gi] += hn;
      }
    }
  }
}

// ---------------- osum/256 -> bf16 ----------------
__global__ void seqenc_conv(const float* __restrict__ osum, u16* __restrict__ ob)
{
  int i = blockIdx.x * blockDim.x + threadIdx.x;
  if (i < 512 * 256) ob[i] = f2bf(osum[i] * (1.0f / 256.0f));
}

extern "C" void kernel_launch(void* const* d_in, const int* in_sizes, int n_in,
                              void* d_out, int out_size, void* d_ws, size_t ws_size,
                              hipStream_t stream) {
  (void)in_sizes; (void)n_in; (void)out_size; (void)ws_size;
  const float* state = (const float*)d_in[0];
  const float* actions = (const float*)d_in[1];
  const float* h0 = (const float*)d_in[2];
  const float* c0 = (const float*)d_in[3];
  const float* w0 = (const float*)d_in[4];
  const float* b0 = (const float*)d_in[5];
  const float* w1 = (const float*)d_in[6];
  const float* b1 = (const float*)d_in[7];
  const float* w2 = (const float*)d_in[8];
  const float* b2 = (const float*)d_in[9];
  const float* w3 = (const float*)d_in[10];
  const float* b3 = (const float*)d_in[11];
  const float* wih = (const float*)d_in[12];
  const float* whh = (const float*)d_in[13];
  const float* bih = (const float*)d_in[14];
  const float* bhh = (const float*)d_in[15];
  const float* wq = (const float*)d_in[16];
  const float* bq = (const float*)d_in[17];
  const float* wk = (const float*)d_in[18];
  const float* bk = (const float*)d_in[19];
  const float* wv = (const float*)d_in[20];
  const float* bv = (const float*)d_in[21];
  const float* wout = (const float*)d_in[22];
  const float* bout = (const float*)d_in[23];

  char* ws = (char*)d_ws;
  size_t off = 0;
  auto take = [&](size_t bytes) {
    off = (off + 255) & ~(size_t)255;
    char* p = ws + off;
    off += bytes;
    return p;
  };
  u16* XpadC = (u16*)take(32768UL * 192 * 2);
  u16* ping  = (u16*)take(32768UL * 512 * 2);
  u16* pong  = (u16*)take(32768UL * 512 * 2);
  u16* X4    = (u16*)take(131072UL * 256 * 2);
  u16* W0p   = (u16*)take(512UL * 192 * 2);
  u16* W1b   = (u16*)take(512UL * 512 * 2);
  u16* W2b   = (u16*)take(512UL * 512 * 2);
  u16* W3b   = (u16*)take(256UL * 512 * 2);
  u16* WcatI = (u16*)take(1024UL * 512 * 2);
  u16* Wqkv  = (u16*)take(768UL * 256 * 2);
  u16* WoutB = (u16*)take(256UL * 256 * 2);
  float* bgI   = (float*)take(1024UL * 4);
  float* bqkvp = (float*)take(768UL * 4);
  u16* QKV   = (u16*)take(512UL * 768 * 2);
  u16* vT    = (u16*)take(256UL * 512 * 2);
  u16* hbuf  = (u16*)take(512UL * 256 * 2);   // h'' (post-attn), input to gates
  u16* hq    = (u16*)take(512UL * 256 * 2);   // h' (post-lstm), input to qkv/attn
  float* cbuf  = (float*)take(512UL * 256 * 4);
  float* osum  = (float*)take(512UL * 256 * 4);
  u16* ob    = (u16*)take(512UL * 256 * 2);

  seqenc_prep_w<<<1024, 256, 0, stream>>>(w0, w1, w2, w3, wih, whh, bih, bhh,
                                          wq, wk, wv, bq, bk, bv, wout,
                                          WcatI, Wqkv, W0p, W1b, W2b, W3b, WoutB, bgI, bqkvp);
  seqenc_init<<<512, 256, 0, stream>>>(h0, c0, hbuf, cbuf, osum);

  const int CM = 32768;
  for (int c = 0; c < 4; ++c) {
    u16* x4c = X4 + (size_t)c * CM * 256;
    seqenc_prep_x<<<2048, 256, 0, stream>>>(state, actions, XpadC, c * 64);
    seqenc_gemm<<<dim3(CM / 128, 4), 256, 0, stream>>>(XpadC, XpadC, 192, 192, W0p, b0, ping, 512, nullptr, 192, 512, 1);
    seqenc_gemm<<<dim3(CM / 128, 4), 256, 0, stream>>>(ping, ping, 512, 512, W1b, b1, pong, 512, nullptr, 512, 512, 1);
    seqenc_gemm<<<dim3(CM / 128, 4), 256, 0, stream>>>(pong, pong, 512, 512, W2b, b2, ping, 512, nullptr, 512, 512, 1);
    seqenc_gemm<<<dim3(CM / 128, 2), 256, 0, stream>>>(ping, ping, 512, 512, W3b, b3, x4c, 256, nullptr, 512, 256, 0);
  }

  for (int t = 0; t < 256; ++t) {
    const u16* xt = X4 + (size_t)t * 512 * 256;
    seqenc_gates_lstm<<<dim3(4, 8), 256, 0, stream>>>(xt, hbuf, WcatI, bgI, cbuf, hq);
    seqenc_gemm<<<dim3(4, 6), 256, 0, stream>>>(hq, hq, 256, 256, Wqkv, bqkvp, QKV, 768, vT, 256, 768, 3);
    seqenc_attn<<<32, 512, 0, stream>>>(QKV, vT, hq, hbuf, osum);
  }

  seqenc_conv<<<512, 256, 0, stream>>>(osum, ob);
  seqenc_gemm<<<dim3(4, 2), 256, 0, stream>>>(ob, ob, 256, 256, WoutB, bout, d_out, 256, nullptr, 256, 256, 2);
}